// Round 2
// baseline (3785.081 us; speedup 1.0000x reference)
//
#include <hip/hip_runtime.h>

#define N_NODES 150000
#define N_EDGES 500000
#define D 128
#define D2 256
#define NLAYER 5

typedef __attribute__((ext_vector_type(8))) short bf16x8;
typedef __attribute__((ext_vector_type(4))) float f32x4;
typedef __attribute__((ext_vector_type(2))) unsigned short ushort2v;
typedef __attribute__((ext_vector_type(4))) unsigned short ushort4v;

__device__ __forceinline__ unsigned short f2bf(float f) {
    unsigned int u = __builtin_bit_cast(unsigned int, f);
    u += 0x7fffu + ((u >> 16) & 1u);
    return (unsigned short)(u >> 16);
}
__device__ __forceinline__ float bf2f(unsigned short s) {
    unsigned int u = ((unsigned int)s) << 16;
    return __builtin_bit_cast(float, u);
}

// ---------------- weight transpose + bf16 convert (once per call) ----------------
// W1 [L][128][256] -> w1t [L][256][128] (bf16);  W2 [L][256][128] -> w2t [L][128][256]
__global__ __launch_bounds__(256) void prepw_kernel(const float* __restrict__ W1,
        const float* __restrict__ W2, unsigned short* __restrict__ w1t,
        unsigned short* __restrict__ w2t) {
    int i = blockIdx.x * 256 + threadIdx.x;
    if (i < NLAYER * D2 * D) {
        int l = i / (D2 * D);
        int rem = i % (D2 * D);
        int n = rem / D;
        int k = rem % D;
        w1t[i] = f2bf(W1[(l * D + k) * D2 + n]);
    }
    if (i < NLAYER * D * D2) {
        int l = i / (D * D2);
        int rem = i % (D * D2);
        int n = rem / D2;
        int k = rem % D2;
        w2t[i] = f2bf(W2[(l * D2 + k) * D + n]);
    }
}

// ---------------- atom encoder: h[n][d] = sum_f atom_emb[f][x[n][f]][d] ----------------
__global__ __launch_bounds__(128) void atom_enc_kernel(const int* __restrict__ x,
        const float* __restrict__ aemb, float* __restrict__ h) {
    int n = blockIdx.x;
    int d = threadIdx.x;
    __shared__ int xi[9];
    if (d < 9) xi[d] = x[n * 9 + d];
    __syncthreads();
    float s = 0.f;
#pragma unroll
    for (int f = 0; f < 9; ++f)
        s += aemb[(f * 119 + xi[f]) * D + d];
    h[n * D + d] = s;
}

// ---------------- message + scatter-add ----------------
__global__ __launch_bounds__(256) void scatter_kernel(const int* __restrict__ ei,
        const int* __restrict__ ea, const float* __restrict__ bemb,
        const float* __restrict__ h, float* __restrict__ aggr) {
    int e = blockIdx.x * 2 + (threadIdx.x >> 7);
    int d = threadIdx.x & 127;
    if (e >= N_EDGES) return;
    int src = ei[e];
    int dst = ei[N_EDGES + e];
    int a0 = ea[e * 3 + 0], a1 = ea[e * 3 + 1], a2 = ea[e * 3 + 2];
    float ev = bemb[(0 * 6 + a0) * D + d] + bemb[(1 * 6 + a1) * D + d]
             + bemb[(2 * 6 + a2) * D + d];
    float m = h[src * D + d] + ev;
    m = fmaxf(m, 0.f);
    atomicAdd(&aggr[dst * D + d], m);
}

// ---------------- GEMM1: z1 = bf16( ((1+eps)h + aggr) @ W1 + b1 ) ----------------
// block = 4 waves, tile 64 rows x 256 cols; wave w -> rows [w*16, w*16+16)
__global__ __launch_bounds__(256) void gemm1_kernel(const float* __restrict__ h,
        const float* __restrict__ aggr, const unsigned short* __restrict__ w1t,
        const float* __restrict__ b1, const float* __restrict__ epsp,
        unsigned short* __restrict__ z1) {
    const float ke = 1.0f + epsp[0];
    int wave = threadIdx.x >> 6;
    int lane = threadIdx.x & 63;
    int l15 = lane & 15;
    int kg = lane >> 4;
    int row = blockIdx.x * 64 + wave * 16 + l15;
    bool valid = row < N_NODES;

    bf16x8 af[4];
#pragma unroll
    for (int kk = 0; kk < 4; ++kk) {
        int k0 = kk * 32 + kg * 8;
        f32x4 ha = {0,0,0,0}, hb = {0,0,0,0}, ga = {0,0,0,0}, gb = {0,0,0,0};
        if (valid) {
            const f32x4* hp = (const f32x4*)(h + row * D + k0);
            const f32x4* gp = (const f32x4*)(aggr + row * D + k0);
            ha = hp[0]; hb = hp[1];
            ga = gp[0]; gb = gp[1];
        }
        bf16x8 a;
#pragma unroll
        for (int j = 0; j < 4; ++j) {
            a[j]     = (short)f2bf(ke * ha[j] + ga[j]);
            a[j + 4] = (short)f2bf(ke * hb[j] + gb[j]);
        }
        af[kk] = a;
    }

    f32x4 acc[16];
#pragma unroll
    for (int t = 0; t < 16; ++t) acc[t] = (f32x4){0,0,0,0};

#pragma unroll
    for (int kk = 0; kk < 4; ++kk) {
#pragma unroll
        for (int t = 0; t < 16; ++t) {
            bf16x8 b = *(const bf16x8*)(w1t + (t * 16 + l15) * D + kk * 32 + kg * 8);
            acc[t] = __builtin_amdgcn_mfma_f32_16x16x32_bf16(af[kk], b, acc[t], 0, 0, 0);
        }
    }

    int orow = blockIdx.x * 64 + wave * 16 + kg * 4;
#pragma unroll
    for (int t = 0; t < 16; ++t) {
        int col = t * 16 + l15;
        float bias = b1[col];
#pragma unroll
        for (int r = 0; r < 4; ++r) {
            int rr = orow + r;
            if (rr < N_NODES)
                z1[rr * D2 + col] = f2bf(acc[t][r] + bias);
        }
    }
}

// ---------------- GEMM2: z2 = bf16( relu(bn1(z1)) @ W2 + b2 ) ----------------
__global__ __launch_bounds__(256) void gemm2_kernel(const unsigned short* __restrict__ z1,
        const float* __restrict__ scale, const float* __restrict__ shift,
        const unsigned short* __restrict__ w2t, const float* __restrict__ b2,
        unsigned short* __restrict__ z2) {
    int wave = threadIdx.x >> 6;
    int lane = threadIdx.x & 63;
    int l15 = lane & 15;
    int kg = lane >> 4;
    int row = blockIdx.x * 64 + wave * 16 + l15;
    bool valid = row < N_NODES;

    f32x4 acc[8];
#pragma unroll
    for (int t = 0; t < 8; ++t) acc[t] = (f32x4){0,0,0,0};

#pragma unroll
    for (int kk = 0; kk < 8; ++kk) {
        int k0 = kk * 32 + kg * 8;
        bf16x8 a = (bf16x8){0,0,0,0,0,0,0,0};
        if (valid) {
            bf16x8 zraw = *(const bf16x8*)(z1 + row * D2 + k0);
            const f32x4* sp = (const f32x4*)(scale + k0);
            const f32x4* tp = (const f32x4*)(shift + k0);
            f32x4 s0 = sp[0], s1 = sp[1], t0 = tp[0], t1 = tp[1];
#pragma unroll
            for (int j = 0; j < 4; ++j) {
                float v0 = fmaxf(bf2f((unsigned short)zraw[j]) * s0[j] + t0[j], 0.f);
                float v1 = fmaxf(bf2f((unsigned short)zraw[j + 4]) * s1[j] + t1[j], 0.f);
                a[j]     = (short)f2bf(v0);
                a[j + 4] = (short)f2bf(v1);
            }
        }
#pragma unroll
        for (int t = 0; t < 8; ++t) {
            bf16x8 b = *(const bf16x8*)(w2t + (t * 16 + l15) * D2 + kk * 32 + kg * 8);
            acc[t] = __builtin_amdgcn_mfma_f32_16x16x32_bf16(a, b, acc[t], 0, 0, 0);
        }
    }

    int orow = blockIdx.x * 64 + wave * 16 + kg * 4;
#pragma unroll
    for (int t = 0; t < 8; ++t) {
        int col = t * 16 + l15;
        float bias = b2[col];
#pragma unroll
        for (int r = 0; r < 4; ++r) {
            int rr = orow + r;
            if (rr < N_NODES)
                z2[rr * D + col] = f2bf(acc[t][r] + bias);
        }
    }
}

// ---------------- per-column sum / sumsq over rows (for BN batch stats) ----------------
__global__ __launch_bounds__(256) void colstats_kernel(const unsigned short* __restrict__ z,
        int C, float* __restrict__ sums) {
    int half = C >> 1;                 // cols handled in pairs
    int c2 = threadIdx.x % half;
    int rsub = threadIdx.x / half;
    int rstep = 256 / half;
    int r0 = blockIdx.x * 256 + rsub;
    int rend = min(N_NODES, (int)(blockIdx.x * 256 + 256));
    float s0 = 0, s1 = 0, q0 = 0, q1 = 0;
    for (int r = r0; r < rend; r += rstep) {
        ushort2v v = *(const ushort2v*)(z + r * C + c2 * 2);
        float x0 = bf2f(v[0]), x1 = bf2f(v[1]);
        s0 += x0; s1 += x1; q0 += x0 * x0; q1 += x1 * x1;
    }
    atomicAdd(&sums[c2 * 2 + 0], s0);
    atomicAdd(&sums[c2 * 2 + 1], s1);
    atomicAdd(&sums[C + c2 * 2 + 0], q0);
    atomicAdd(&sums[C + c2 * 2 + 1], q1);
}

__global__ void finalize_kernel(const float* __restrict__ sums, const float* __restrict__ g,
        const float* __restrict__ b, int C, float* __restrict__ scale,
        float* __restrict__ shift) {
    int c = threadIdx.x;
    if (c < C) {
        float inv_n = 1.0f / (float)N_NODES;
        float mean = sums[c] * inv_n;
        float var = sums[C + c] * inv_n - mean * mean;
        float sc = g[c] * rsqrtf(var + 1e-5f);
        scale[c] = sc;
        shift[c] = b[c] - mean * sc;
    }
}

// ---------------- final: h = (relu?)(bn2(z2)) + h ----------------
__global__ __launch_bounds__(256) void final_kernel(const unsigned short* __restrict__ z2,
        const float* __restrict__ scale, const float* __restrict__ shift,
        float* __restrict__ h, int do_relu) {
    int i = blockIdx.x * 256 + threadIdx.x;
    int base = i * 4;
    int c = base & (D - 1);
    f32x4 sc = *(const f32x4*)(scale + c);
    f32x4 sh = *(const f32x4*)(shift + c);
    ushort4v zv = *(const ushort4v*)(z2 + base);
    f32x4 hv = *(const f32x4*)(h + base);
    f32x4 o;
#pragma unroll
    for (int j = 0; j < 4; ++j) {
        float v = bf2f(zv[j]) * sc[j] + sh[j];
        if (do_relu) v = fmaxf(v, 0.f);
        o[j] = v + hv[j];
    }
    *(f32x4*)(h + base) = o;
}

extern "C" void kernel_launch(void* const* d_in, const int* in_sizes, int n_in,
                              void* d_out, int out_size, void* d_ws, size_t ws_size,
                              hipStream_t stream) {
    const int* x = (const int*)d_in[0];
    const int* ei = (const int*)d_in[1];
    const int* ea = (const int*)d_in[2];
    const float* aemb = (const float*)d_in[4];
    const float* bemb = (const float*)d_in[5];
    const float* eps = (const float*)d_in[6];
    const float* W1 = (const float*)d_in[7];
    const float* b1 = (const float*)d_in[8];
    const float* bn1g = (const float*)d_in[9];
    const float* bn1b = (const float*)d_in[10];
    const float* W2 = (const float*)d_in[11];
    const float* b2 = (const float*)d_in[12];
    const float* bng = (const float*)d_in[13];
    const float* bnb = (const float*)d_in[14];
    float* h = (float*)d_out;

    char* ws = (char*)d_ws;
    size_t off = 0;
    unsigned short* z1 = (unsigned short*)(ws + off); off += (size_t)N_NODES * D2 * 2;  // 76.8MB
    float* aggr = (float*)(ws + off);                                                    // 76.8MB
    unsigned short* z2 = (unsigned short*)(ws + off); off += (size_t)N_NODES * D * 4;   // z2 aliases aggr
    unsigned short* w1t = (unsigned short*)(ws + off); off += (size_t)NLAYER * D2 * D * 2;
    unsigned short* w2t = (unsigned short*)(ws + off); off += (size_t)NLAYER * D * D2 * 2;
    float* stats = (float*)(ws + off);
    float* scale = stats + 512;
    float* shift = stats + 768;

    prepw_kernel<<<(NLAYER * D2 * D + 255) / 256, 256, 0, stream>>>(W1, W2, w1t, w2t);
    atom_enc_kernel<<<N_NODES, 128, 0, stream>>>(x, aemb, h);

    for (int l = 0; l < NLAYER; ++l) {
        hipMemsetAsync(aggr, 0, (size_t)N_NODES * D * 4, stream);
        hipMemsetAsync(stats, 0, 512 * 4, stream);
        scatter_kernel<<<(N_EDGES + 1) / 2, 256, 0, stream>>>(ei, ea, bemb + l * 3 * 6 * D, h, aggr);
        gemm1_kernel<<<(N_NODES + 63) / 64, 256, 0, stream>>>(h, aggr, w1t + l * D2 * D,
                b1 + l * D2, eps + l, z1);
        colstats_kernel<<<(N_NODES + 255) / 256, 256, 0, stream>>>(z1, D2, stats);
        finalize_kernel<<<1, D2, 0, stream>>>(stats, bn1g + l * D2, bn1b + l * D2, D2, scale, shift);
        gemm2_kernel<<<(N_NODES + 63) / 64, 256, 0, stream>>>(z1, scale, shift, w2t + l * D * D2,
                b2 + l * D, z2);
        hipMemsetAsync(stats, 0, 512 * 4, stream);
        colstats_kernel<<<(N_NODES + 255) / 256, 256, 0, stream>>>(z2, D, stats);
        finalize_kernel<<<1, D, 0, stream>>>(stats, bng + l * D, bnb + l * D, D, scale, shift);
        final_kernel<<<(N_NODES * D / 4) / 256, 256, 0, stream>>>(z2, scale, shift, h,
                (l < NLAYER - 1) ? 1 : 0);
    }
}

// Round 3
// 2064.756 us; speedup vs baseline: 1.8332x; 1.8332x over previous
//
#include <hip/hip_runtime.h>

#define N_NODES 150000
#define N_EDGES 500000
#define D 128
#define D2 256
#define NLAYER 5
#define NB1 586   // ceil(N_NODES/256)

typedef __attribute__((ext_vector_type(8))) short bf16x8;
typedef __attribute__((ext_vector_type(4))) float f32x4;
typedef __attribute__((ext_vector_type(4))) unsigned short ushort4v;

__device__ __forceinline__ unsigned short f2bf(float f) {
    unsigned int u = __builtin_bit_cast(unsigned int, f);
    u += 0x7fffu + ((u >> 16) & 1u);
    return (unsigned short)(u >> 16);
}
__device__ __forceinline__ float bf2f(unsigned short s) {
    unsigned int u = ((unsigned int)s) << 16;
    return __builtin_bit_cast(float, u);
}

// ---------------- weight transpose + bf16 convert ----------------
__global__ __launch_bounds__(256) void prepw_kernel(const float* __restrict__ W1,
        const float* __restrict__ W2, unsigned short* __restrict__ w1t,
        unsigned short* __restrict__ w2t) {
    int i = blockIdx.x * 256 + threadIdx.x;
    if (i < NLAYER * D2 * D) {
        int l = i / (D2 * D);
        int rem = i % (D2 * D);
        int n = rem / D;
        int k = rem % D;
        w1t[i] = f2bf(W1[(l * D + k) * D2 + n]);
    }
    if (i < NLAYER * D * D2) {
        int l = i / (D * D2);
        int rem = i % (D * D2);
        int n = rem / D2;
        int k = rem % D2;
        w2t[i] = f2bf(W2[(l * D2 + k) * D + n]);
    }
}

// ---------------- bond combo table: combo[l][p][d], p = a0 + 6*a1 + 36*a2 ----------------
__global__ __launch_bounds__(128) void combo_kernel(const float* __restrict__ bemb,
        float* __restrict__ combo) {
    int b = blockIdx.x;            // l*216 + p
    int l = b / 216, p = b % 216;
    int a0 = p % 6, a1 = (p / 6) % 6, a2 = p / 36;
    int d = threadIdx.x;
    combo[b * D + d] = bemb[((l * 3 + 0) * 6 + a0) * D + d]
                     + bemb[((l * 3 + 1) * 6 + a1) * D + d]
                     + bemb[((l * 3 + 2) * 6 + a2) * D + d];
}

// ---------------- atom encoder ----------------
__global__ __launch_bounds__(256) void atom_enc_kernel(const int* __restrict__ x,
        const float* __restrict__ aemb, float* __restrict__ h) {
    int node = blockIdx.x * 8 + (threadIdx.x >> 5);
    int t = threadIdx.x & 31;
    int d0 = t * 4;
    f32x4 s = {0, 0, 0, 0};
#pragma unroll
    for (int f = 0; f < 9; ++f) {
        int xi = x[node * 9 + f];
        f32x4 v = *(const f32x4*)(aemb + (size_t)(f * 119 + xi) * D + d0);
        s[0] += v[0]; s[1] += v[1]; s[2] += v[2]; s[3] += v[3];
    }
    *(f32x4*)(h + (size_t)node * D + d0) = s;
}

// ---------------- CSR build ----------------
__global__ __launch_bounds__(256) void hist_kernel(const int* __restrict__ ei,
        int* __restrict__ deg) {
    int e = blockIdx.x * 256 + threadIdx.x;
    if (e < N_EDGES) atomicAdd(&deg[ei[N_EDGES + e]], 1);
}

__global__ __launch_bounds__(256) void scan1_kernel(const int* __restrict__ deg,
        int* __restrict__ part, int* __restrict__ bsum) {
    __shared__ int sd[256];
    int tid = threadIdx.x;
    int i = blockIdx.x * 256 + tid;
    int v = (i < N_NODES) ? deg[i] : 0;
    sd[tid] = v;
    __syncthreads();
    for (int off = 1; off < 256; off <<= 1) {
        int t = (tid >= off) ? sd[tid - off] : 0;
        __syncthreads();
        sd[tid] += t;
        __syncthreads();
    }
    if (i < N_NODES) part[i] = sd[tid] - v;
    if (tid == 255) bsum[blockIdx.x] = sd[255];
}

__global__ __launch_bounds__(1024) void scan2_kernel(const int* __restrict__ bsum,
        int* __restrict__ boff) {
    __shared__ int sd[1024];
    int tid = threadIdx.x;
    int v = (tid < NB1) ? bsum[tid] : 0;
    sd[tid] = v;
    __syncthreads();
    for (int off = 1; off < 1024; off <<= 1) {
        int t = (tid >= off) ? sd[tid - off] : 0;
        __syncthreads();
        sd[tid] += t;
        __syncthreads();
    }
    if (tid < NB1) boff[tid] = sd[tid] - v;
}

__global__ __launch_bounds__(256) void scan3_kernel(const int* __restrict__ part,
        const int* __restrict__ boff, int* __restrict__ row_start) {
    int i = blockIdx.x * 256 + threadIdx.x;
    if (i < N_NODES) row_start[i] = part[i] + boff[i >> 8];
}

__global__ __launch_bounds__(256) void bin_kernel(const int* __restrict__ ei,
        const int* __restrict__ ea, const int* __restrict__ row_start,
        int* __restrict__ cursor, int* __restrict__ bins) {
    int e = blockIdx.x * 256 + threadIdx.x;
    if (e >= N_EDGES) return;
    int dst = ei[N_EDGES + e];
    int pos = row_start[dst] + atomicAdd(&cursor[dst], 1);
    int pack = ea[e * 3 + 0] + ea[e * 3 + 1] * 6 + ea[e * 3 + 2] * 36;
    bins[pos] = ei[e] | (pack << 18);
}

// ---------------- aggregation + A-build: A = bf16((1+eps)h + sum relu(h[src]+e)) ----------------
__global__ __launch_bounds__(256) void aggr_kernel(const int* __restrict__ row_start,
        const int* __restrict__ deg, const int* __restrict__ bins,
        const float* __restrict__ combo, const float* __restrict__ h,
        const float* __restrict__ epsp, unsigned short* __restrict__ A) {
    int node = blockIdx.x * 8 + (threadIdx.x >> 5);
    int t = threadIdx.x & 31;
    int d0 = t * 4;
    float ke = 1.0f + epsp[0];
    int start = row_start[node];
    int dg = deg[node];
    f32x4 s = {0, 0, 0, 0};
    int entry = (dg > 0) ? bins[start] : 0;
    for (int i = 0; i < dg; ++i) {
        int next = (i + 1 < dg) ? bins[start + i + 1] : 0;
        int src = entry & 0x3FFFF;
        int pack = entry >> 18;
        f32x4 hv = *(const f32x4*)(h + (size_t)src * D + d0);
        f32x4 cv = *(const f32x4*)(combo + pack * D + d0);
#pragma unroll
        for (int j = 0; j < 4; ++j) s[j] += fmaxf(hv[j] + cv[j], 0.f);
        entry = next;
    }
    f32x4 hs = *(const f32x4*)(h + (size_t)node * D + d0);
    ushort4v o;
#pragma unroll
    for (int j = 0; j < 4; ++j) o[j] = f2bf(ke * hs[j] + s[j]);
    *(ushort4v*)(A + (size_t)node * D + d0) = o;
}

// ---------------- GEMM1: z1 = bf16(A @ W1 + b1), fused column stats ----------------
__global__ __launch_bounds__(256) void gemm1_kernel(const unsigned short* __restrict__ A,
        const unsigned short* __restrict__ w1t, const float* __restrict__ b1,
        unsigned short* __restrict__ z1, float* __restrict__ gsum, float* __restrict__ gsq) {
    __shared__ float ssum[D2], ssq[D2];
    ssum[threadIdx.x] = 0.f;
    ssq[threadIdx.x] = 0.f;
    __syncthreads();
    int wave = threadIdx.x >> 6;
    int lane = threadIdx.x & 63;
    int l15 = lane & 15;
    int kg = lane >> 4;
    int row = blockIdx.x * 64 + wave * 16 + l15;
    bool valid = row < N_NODES;

    bf16x8 af[4];
#pragma unroll
    for (int kk = 0; kk < 4; ++kk)
        af[kk] = valid ? *(const bf16x8*)(A + (size_t)row * D + kk * 32 + kg * 8)
                       : (bf16x8){0,0,0,0,0,0,0,0};

    f32x4 acc[16];
#pragma unroll
    for (int t = 0; t < 16; ++t) acc[t] = (f32x4){0,0,0,0};
#pragma unroll
    for (int kk = 0; kk < 4; ++kk) {
#pragma unroll
        for (int t = 0; t < 16; ++t) {
            bf16x8 b = *(const bf16x8*)(w1t + (t * 16 + l15) * D + kk * 32 + kg * 8);
            acc[t] = __builtin_amdgcn_mfma_f32_16x16x32_bf16(af[kk], b, acc[t], 0, 0, 0);
        }
    }

    int orow = blockIdx.x * 64 + wave * 16 + kg * 4;
#pragma unroll
    for (int t = 0; t < 16; ++t) {
        int col = t * 16 + l15;
        float bias = b1[col];
        float sv = 0.f, qv = 0.f;
#pragma unroll
        for (int r = 0; r < 4; ++r) {
            int rr = orow + r;
            if (rr < N_NODES) {
                unsigned short us = f2bf(acc[t][r] + bias);
                z1[(size_t)rr * D2 + col] = us;
                float v = bf2f(us);
                sv += v;
                qv += v * v;
            }
        }
        sv += __shfl_xor(sv, 16); sv += __shfl_xor(sv, 32);
        qv += __shfl_xor(qv, 16); qv += __shfl_xor(qv, 32);
        if (kg == (t & 3)) {
            atomicAdd(&ssum[col], sv);
            atomicAdd(&ssq[col], qv);
        }
    }
    __syncthreads();
    atomicAdd(&gsum[threadIdx.x], ssum[threadIdx.x]);
    atomicAdd(&gsq[threadIdx.x], ssq[threadIdx.x]);
}

__global__ void finalize_kernel(const float* __restrict__ sum, const float* __restrict__ sq,
        const float* __restrict__ g, const float* __restrict__ b, int C,
        float* __restrict__ scale, float* __restrict__ shift) {
    int c = threadIdx.x;
    if (c < C) {
        float inv_n = 1.0f / (float)N_NODES;
        float mean = sum[c] * inv_n;
        float var = sq[c] * inv_n - mean * mean;
        float sc = g[c] * rsqrtf(var + 1e-5f);
        scale[c] = sc;
        shift[c] = b[c] - mean * sc;
    }
}

// ---------------- GEMM2: z2 = bf16(relu(bn1(z1)) @ W2 + b2), fused stats ----------------
__global__ __launch_bounds__(256) void gemm2_kernel(const unsigned short* __restrict__ z1,
        const float* __restrict__ scale, const float* __restrict__ shift,
        const unsigned short* __restrict__ w2t, const float* __restrict__ b2,
        unsigned short* __restrict__ z2, float* __restrict__ gsum, float* __restrict__ gsq) {
    __shared__ float ssum[D], ssq[D];
    if (threadIdx.x < D) {
        ssum[threadIdx.x] = 0.f;
        ssq[threadIdx.x] = 0.f;
    }
    __syncthreads();
    int wave = threadIdx.x >> 6;
    int lane = threadIdx.x & 63;
    int l15 = lane & 15;
    int kg = lane >> 4;
    int row = blockIdx.x * 64 + wave * 16 + l15;
    bool valid = row < N_NODES;

    f32x4 acc[8];
#pragma unroll
    for (int t = 0; t < 8; ++t) acc[t] = (f32x4){0,0,0,0};

#pragma unroll
    for (int kk = 0; kk < 8; ++kk) {
        int k0 = kk * 32 + kg * 8;
        bf16x8 a = (bf16x8){0,0,0,0,0,0,0,0};
        if (valid) {
            bf16x8 zraw = *(const bf16x8*)(z1 + (size_t)row * D2 + k0);
            const f32x4* sp = (const f32x4*)(scale + k0);
            const f32x4* tp = (const f32x4*)(shift + k0);
            f32x4 s0 = sp[0], s1 = sp[1], t0 = tp[0], t1 = tp[1];
#pragma unroll
            for (int j = 0; j < 4; ++j) {
                float v0 = fmaxf(bf2f((unsigned short)zraw[j]) * s0[j] + t0[j], 0.f);
                float v1 = fmaxf(bf2f((unsigned short)zraw[j + 4]) * s1[j] + t1[j], 0.f);
                a[j]     = (short)f2bf(v0);
                a[j + 4] = (short)f2bf(v1);
            }
        }
#pragma unroll
        for (int t = 0; t < 8; ++t) {
            bf16x8 b = *(const bf16x8*)(w2t + (t * 16 + l15) * D2 + kk * 32 + kg * 8);
            acc[t] = __builtin_amdgcn_mfma_f32_16x16x32_bf16(a, b, acc[t], 0, 0, 0);
        }
    }

    int orow = blockIdx.x * 64 + wave * 16 + kg * 4;
#pragma unroll
    for (int t = 0; t < 8; ++t) {
        int col = t * 16 + l15;
        float bias = b2[col];
        float sv = 0.f, qv = 0.f;
#pragma unroll
        for (int r = 0; r < 4; ++r) {
            int rr = orow + r;
            if (rr < N_NODES) {
                unsigned short us = f2bf(acc[t][r] + bias);
                z2[(size_t)rr * D + col] = us;
                float v = bf2f(us);
                sv += v;
                qv += v * v;
            }
        }
        sv += __shfl_xor(sv, 16); sv += __shfl_xor(sv, 32);
        qv += __shfl_xor(qv, 16); qv += __shfl_xor(qv, 32);
        if (kg == (t & 3)) {
            atomicAdd(&ssum[col], sv);
            atomicAdd(&ssq[col], qv);
        }
    }
    __syncthreads();
    if (threadIdx.x < D) {
        atomicAdd(&gsum[threadIdx.x], ssum[threadIdx.x]);
        atomicAdd(&gsq[threadIdx.x], ssq[threadIdx.x]);
    }
}

// ---------------- final: h = (relu?)(bn2(z2)) + h ----------------
__global__ __launch_bounds__(256) void final_kernel(const unsigned short* __restrict__ z2,
        const float* __restrict__ scale, const float* __restrict__ shift,
        float* __restrict__ h, int do_relu) {
    int i = blockIdx.x * 256 + threadIdx.x;
    int base = i * 4;
    int c = base & (D - 1);
    f32x4 sc = *(const f32x4*)(scale + c);
    f32x4 sh = *(const f32x4*)(shift + c);
    ushort4v zv = *(const ushort4v*)(z2 + base);
    f32x4 hv = *(const f32x4*)(h + base);
    f32x4 o;
#pragma unroll
    for (int j = 0; j < 4; ++j) {
        float v = bf2f(zv[j]) * sc[j] + sh[j];
        if (do_relu) v = fmaxf(v, 0.f);
        o[j] = v + hv[j];
    }
    *(f32x4*)(h + base) = o;
}

extern "C" void kernel_launch(void* const* d_in, const int* in_sizes, int n_in,
                              void* d_out, int out_size, void* d_ws, size_t ws_size,
                              hipStream_t stream) {
    const int* x = (const int*)d_in[0];
    const int* ei = (const int*)d_in[1];
    const int* ea = (const int*)d_in[2];
    const float* aemb = (const float*)d_in[4];
    const float* bemb = (const float*)d_in[5];
    const float* eps = (const float*)d_in[6];
    const float* W1 = (const float*)d_in[7];
    const float* b1 = (const float*)d_in[8];
    const float* bn1g = (const float*)d_in[9];
    const float* bn1b = (const float*)d_in[10];
    const float* W2 = (const float*)d_in[11];
    const float* b2 = (const float*)d_in[12];
    const float* bng = (const float*)d_in[13];
    const float* bnb = (const float*)d_in[14];
    float* h = (float*)d_out;

    char* ws = (char*)d_ws;
    size_t off = 0;
    auto alloc = [&](size_t bytes) {
        void* p = ws + off;
        off += (bytes + 255) & ~(size_t)255;
        return p;
    };
    unsigned short* z1  = (unsigned short*)alloc((size_t)N_NODES * D2 * 2);  // 76.8MB
    unsigned short* Az2 = (unsigned short*)alloc((size_t)N_NODES * D * 2);   // 38.4MB (A aliases z2)
    unsigned short* w1t = (unsigned short*)alloc((size_t)NLAYER * D2 * D * 2);
    unsigned short* w2t = (unsigned short*)alloc((size_t)NLAYER * D * D2 * 2);
    float* combo        = (float*)alloc((size_t)NLAYER * 216 * D * 4);
    int* bins           = (int*)alloc((size_t)N_EDGES * 4);
    int* row_start      = (int*)alloc((size_t)(NB1 * 256) * 4);
    int* deg            = (int*)alloc((size_t)(NB1 * 256) * 4);
    int* cursor         = (int*)alloc((size_t)(NB1 * 256) * 4);
    int* part           = (int*)alloc((size_t)(NB1 * 256) * 4);
    int* bsum           = (int*)alloc(1024 * 4);
    int* boff           = (int*)alloc(1024 * 4);
    float* statsblk     = (float*)alloc(768 * 4);   // gsum1[256] gsq1[256] gsum2[128] gsq2[128]
    float* gsum1 = statsblk, *gsq1 = statsblk + 256, *gsum2 = statsblk + 512, *gsq2 = statsblk + 640;
    float* scale1 = (float*)alloc(256 * 4);
    float* shift1 = (float*)alloc(256 * 4);
    float* scale2 = (float*)alloc(128 * 4);
    float* shift2 = (float*)alloc(128 * 4);

    // one-time prep
    prepw_kernel<<<(NLAYER * D2 * D + 255) / 256, 256, 0, stream>>>(W1, W2, w1t, w2t);
    combo_kernel<<<NLAYER * 216, 128, 0, stream>>>(bemb, combo);
    atom_enc_kernel<<<N_NODES / 8, 256, 0, stream>>>(x, aemb, h);

    // CSR build (by dst)
    hipMemsetAsync(deg, 0, (size_t)(NB1 * 256) * 4, stream);
    hipMemsetAsync(cursor, 0, (size_t)(NB1 * 256) * 4, stream);
    hist_kernel<<<(N_EDGES + 255) / 256, 256, 0, stream>>>(ei, deg);
    scan1_kernel<<<NB1, 256, 0, stream>>>(deg, part, bsum);
    scan2_kernel<<<1, 1024, 0, stream>>>(bsum, boff);
    scan3_kernel<<<NB1, 256, 0, stream>>>(part, boff, row_start);
    bin_kernel<<<(N_EDGES + 255) / 256, 256, 0, stream>>>(ei, ea, row_start, cursor, bins);

    for (int l = 0; l < NLAYER; ++l) {
        hipMemsetAsync(statsblk, 0, 768 * 4, stream);
        aggr_kernel<<<N_NODES / 8, 256, 0, stream>>>(row_start, deg, bins,
                combo + l * 216 * D, h, eps + l, Az2);
        gemm1_kernel<<<(N_NODES + 63) / 64, 256, 0, stream>>>(Az2, w1t + l * D2 * D,
                b1 + l * D2, z1, gsum1, gsq1);
        finalize_kernel<<<1, 256, 0, stream>>>(gsum1, gsq1, bn1g + l * D2, bn1b + l * D2,
                D2, scale1, shift1);
        gemm2_kernel<<<(N_NODES + 63) / 64, 256, 0, stream>>>(z1, scale1, shift1,
                w2t + l * D * D2, b2 + l * D, Az2, gsum2, gsq2);
        finalize_kernel<<<1, 128, 0, stream>>>(gsum2, gsq2, bng + l * D, bnb + l * D,
                D, scale2, shift2);
        final_kernel<<<(N_NODES * D / 4) / 256, 256, 0, stream>>>(Az2, scale2, shift2, h,
                (l < NLAYER - 1) ? 1 : 0);
    }
}

// Round 5
// 1875.445 us; speedup vs baseline: 2.0182x; 1.1009x over previous
//
#include <hip/hip_runtime.h>

#define N_NODES 150000
#define N_EDGES 500000
#define D 128
#define D2 256
#define NLAYER 5
#define NB1 586   // ceil(N_NODES/256)
#define NBG 2344  // ceil(N_NODES/64) gemm blocks

typedef __attribute__((ext_vector_type(8))) short bf16x8;
typedef __attribute__((ext_vector_type(4))) float f32x4;
typedef __attribute__((ext_vector_type(4))) unsigned short ushort4v;

__device__ __forceinline__ unsigned short f2bf(float f) {
    unsigned int u = __builtin_bit_cast(unsigned int, f);
    u += 0x7fffu + ((u >> 16) & 1u);
    return (unsigned short)(u >> 16);
}
__device__ __forceinline__ float bf2f(unsigned short s) {
    unsigned int u = ((unsigned int)s) << 16;
    return __builtin_bit_cast(float, u);
}

// ---------------- weight transpose + bf16 convert ----------------
__global__ __launch_bounds__(256) void prepw_kernel(const float* __restrict__ W1,
        const float* __restrict__ W2, unsigned short* __restrict__ w1t,
        unsigned short* __restrict__ w2t) {
    int i = blockIdx.x * 256 + threadIdx.x;
    if (i < NLAYER * D2 * D) {
        int l = i / (D2 * D);
        int rem = i % (D2 * D);
        int n = rem / D;
        int k = rem % D;
        w1t[i] = f2bf(W1[(l * D + k) * D2 + n]);
    }
    if (i < NLAYER * D * D2) {
        int l = i / (D * D2);
        int rem = i % (D * D2);
        int n = rem / D2;
        int k = rem % D2;
        w2t[i] = f2bf(W2[(l * D2 + k) * D + n]);
    }
}

// ---------------- bond combo table: combo[l][p][d], p = a0 + 6*a1 + 36*a2 ----------------
__global__ __launch_bounds__(128) void combo_kernel(const float* __restrict__ bemb,
        float* __restrict__ combo) {
    int b = blockIdx.x;            // l*216 + p
    int l = b / 216, p = b % 216;
    int a0 = p % 6, a1 = (p / 6) % 6, a2 = p / 36;
    int d = threadIdx.x;
    combo[b * D + d] = bemb[((l * 3 + 0) * 6 + a0) * D + d]
                     + bemb[((l * 3 + 1) * 6 + a1) * D + d]
                     + bemb[((l * 3 + 2) * 6 + a2) * D + d];
}

// ---------------- atom encoder ----------------
__global__ __launch_bounds__(256) void atom_enc_kernel(const int* __restrict__ x,
        const float* __restrict__ aemb, float* __restrict__ h) {
    int node = blockIdx.x * 8 + (threadIdx.x >> 5);
    int t = threadIdx.x & 31;
    int d0 = t * 4;
    f32x4 s = {0, 0, 0, 0};
#pragma unroll
    for (int f = 0; f < 9; ++f) {
        int xi = x[node * 9 + f];
        f32x4 v = *(const f32x4*)(aemb + (size_t)(f * 119 + xi) * D + d0);
        s[0] += v[0]; s[1] += v[1]; s[2] += v[2]; s[3] += v[3];
    }
    *(f32x4*)(h + (size_t)node * D + d0) = s;
}

// ---------------- CSR build ----------------
__global__ __launch_bounds__(256) void hist_kernel(const int* __restrict__ ei,
        int* __restrict__ deg) {
    int e = blockIdx.x * 256 + threadIdx.x;
    if (e < N_EDGES) atomicAdd(&deg[ei[N_EDGES + e]], 1);
}

__global__ __launch_bounds__(256) void scan1_kernel(const int* __restrict__ deg,
        int* __restrict__ part, int* __restrict__ bsum) {
    __shared__ int sd[256];
    int tid = threadIdx.x;
    int i = blockIdx.x * 256 + tid;
    int v = (i < N_NODES) ? deg[i] : 0;
    sd[tid] = v;
    __syncthreads();
    for (int off = 1; off < 256; off <<= 1) {
        int t = (tid >= off) ? sd[tid - off] : 0;
        __syncthreads();
        sd[tid] += t;
        __syncthreads();
    }
    if (i < N_NODES) part[i] = sd[tid] - v;
    if (tid == 255) bsum[blockIdx.x] = sd[255];
}

__global__ __launch_bounds__(1024) void scan2_kernel(const int* __restrict__ bsum,
        int* __restrict__ boff) {
    __shared__ int sd[1024];
    int tid = threadIdx.x;
    int v = (tid < NB1) ? bsum[tid] : 0;
    sd[tid] = v;
    __syncthreads();
    for (int off = 1; off < 1024; off <<= 1) {
        int t = (tid >= off) ? sd[tid - off] : 0;
        __syncthreads();
        sd[tid] += t;
        __syncthreads();
    }
    if (tid < NB1) boff[tid] = sd[tid] - v;
}

__global__ __launch_bounds__(256) void scan3_kernel(const int* __restrict__ part,
        const int* __restrict__ boff, int* __restrict__ row_start) {
    int i = blockIdx.x * 256 + threadIdx.x;
    if (i < N_NODES) row_start[i] = part[i] + boff[i >> 8];
}

__global__ __launch_bounds__(256) void bin_kernel(const int* __restrict__ ei,
        const int* __restrict__ ea, const int* __restrict__ row_start,
        int* __restrict__ cursor, int* __restrict__ bins) {
    int e = blockIdx.x * 256 + threadIdx.x;
    if (e >= N_EDGES) return;
    int dst = ei[N_EDGES + e];
    int pos = row_start[dst] + atomicAdd(&cursor[dst], 1);
    int pack = ea[e * 3 + 0] + ea[e * 3 + 1] * 6 + ea[e * 3 + 2] * 36;
    bins[pos] = ei[e] | (pack << 18);
}

// ---------------- aggregation + A-build: A = bf16((1+eps)h + sum relu(h[src]+e)) ----------------
__global__ __launch_bounds__(256) void aggr_kernel(const int* __restrict__ row_start,
        const int* __restrict__ deg, const int* __restrict__ bins,
        const float* __restrict__ combo, const float* __restrict__ h,
        const float* __restrict__ epsp, unsigned short* __restrict__ A) {
    int node = blockIdx.x * 8 + (threadIdx.x >> 5);
    int t = threadIdx.x & 31;
    int d0 = t * 4;
    float ke = 1.0f + epsp[0];
    int start = row_start[node];
    int dg = deg[node];
    f32x4 s = {0, 0, 0, 0};
    int entry = (dg > 0) ? bins[start] : 0;
    for (int i = 0; i < dg; ++i) {
        int next = (i + 1 < dg) ? bins[start + i + 1] : 0;
        int src = entry & 0x3FFFF;
        int pack = entry >> 18;
        f32x4 hv = *(const f32x4*)(h + (size_t)src * D + d0);
        f32x4 cv = *(const f32x4*)(combo + pack * D + d0);
#pragma unroll
        for (int j = 0; j < 4; ++j) s[j] += fmaxf(hv[j] + cv[j], 0.f);
        entry = next;
    }
    f32x4 hs = *(const f32x4*)(h + (size_t)node * D + d0);
    ushort4v o;
#pragma unroll
    for (int j = 0; j < 4; ++j) o[j] = f2bf(ke * hs[j] + s[j]);
    *(ushort4v*)(A + (size_t)node * D + d0) = o;
}

// ---------------- GEMM1: z1 = bf16(A @ W1 + b1), per-block column partials ----------------
__global__ __launch_bounds__(256) void gemm1_kernel(const unsigned short* __restrict__ A,
        const unsigned short* __restrict__ w1t, const float* __restrict__ b1,
        unsigned short* __restrict__ z1, float* __restrict__ part1) {
    __shared__ float ssum[D2], ssq[D2];
    ssum[threadIdx.x] = 0.f;
    ssq[threadIdx.x] = 0.f;
    __syncthreads();
    int wave = threadIdx.x >> 6;
    int lane = threadIdx.x & 63;
    int l15 = lane & 15;
    int kg = lane >> 4;
    int row = blockIdx.x * 64 + wave * 16 + l15;
    bool valid = row < N_NODES;

    bf16x8 af[4];
#pragma unroll
    for (int kk = 0; kk < 4; ++kk)
        af[kk] = valid ? *(const bf16x8*)(A + (size_t)row * D + kk * 32 + kg * 8)
                       : (bf16x8){0,0,0,0,0,0,0,0};

    f32x4 acc[16];
#pragma unroll
    for (int t = 0; t < 16; ++t) acc[t] = (f32x4){0,0,0,0};
#pragma unroll
    for (int kk = 0; kk < 4; ++kk) {
#pragma unroll
        for (int t = 0; t < 16; ++t) {
            bf16x8 b = *(const bf16x8*)(w1t + (t * 16 + l15) * D + kk * 32 + kg * 8);
            acc[t] = __builtin_amdgcn_mfma_f32_16x16x32_bf16(af[kk], b, acc[t], 0, 0, 0);
        }
    }

    int orow = blockIdx.x * 64 + wave * 16 + kg * 4;
#pragma unroll
    for (int t = 0; t < 16; ++t) {
        int col = t * 16 + l15;
        float bias = b1[col];
        float sv = 0.f, qv = 0.f;
#pragma unroll
        for (int r = 0; r < 4; ++r) {
            int rr = orow + r;
            if (rr < N_NODES) {
                unsigned short us = f2bf(acc[t][r] + bias);
                z1[(size_t)rr * D2 + col] = us;
                float v = bf2f(us);
                sv += v;
                qv += v * v;
            }
        }
        sv += __shfl_xor(sv, 16); sv += __shfl_xor(sv, 32);
        qv += __shfl_xor(qv, 16); qv += __shfl_xor(qv, 32);
        if (kg == (t & 3)) {
            atomicAdd(&ssum[col], sv);
            atomicAdd(&ssq[col], qv);
        }
    }
    __syncthreads();
    part1[(size_t)blockIdx.x * 512 + threadIdx.x] = ssum[threadIdx.x];
    part1[(size_t)blockIdx.x * 512 + 256 + threadIdx.x] = ssq[threadIdx.x];
}

// ---------------- reduce partials + finalize BN: one block per column ----------------
__global__ __launch_bounds__(256) void reduce_finalize_kernel(const float* __restrict__ part,
        int nblk, int C, const float* __restrict__ g, const float* __restrict__ bb,
        float* __restrict__ scale, float* __restrict__ shift) {
    int c = blockIdx.x;
    int tid = threadIdx.x;
    float s = 0.f, q = 0.f;
    for (int i = tid; i < nblk; i += 256) {
        s += part[(size_t)i * 2 * C + c];
        q += part[(size_t)i * 2 * C + C + c];
    }
#pragma unroll
    for (int off = 1; off < 64; off <<= 1) {
        s += __shfl_xor(s, off);
        q += __shfl_xor(q, off);
    }
    __shared__ float rs[4], rq[4];
    int w = tid >> 6;
    if ((tid & 63) == 0) { rs[w] = s; rq[w] = q; }
    __syncthreads();
    if (tid == 0) {
        s = rs[0] + rs[1] + rs[2] + rs[3];
        q = rq[0] + rq[1] + rq[2] + rq[3];
        float inv_n = 1.0f / (float)N_NODES;
        float mean = s * inv_n;
        float var = q * inv_n - mean * mean;
        float sc = g[c] * rsqrtf(var + 1e-5f);
        scale[c] = sc;
        shift[c] = bb[c] - mean * sc;
    }
}

// ---------------- GEMM2: z2 = bf16(relu(bn1(z1)) @ W2 + b2), per-block partials ----------------
__global__ __launch_bounds__(256) void gemm2_kernel(const unsigned short* __restrict__ z1,
        const float* __restrict__ scale, const float* __restrict__ shift,
        const unsigned short* __restrict__ w2t, const float* __restrict__ b2,
        unsigned short* __restrict__ z2, float* __restrict__ part2) {
    __shared__ float ssum[D], ssq[D];
    if (threadIdx.x < D) {
        ssum[threadIdx.x] = 0.f;
        ssq[threadIdx.x] = 0.f;
    }
    __syncthreads();
    int wave = threadIdx.x >> 6;
    int lane = threadIdx.x & 63;
    int l15 = lane & 15;
    int kg = lane >> 4;
    int row = blockIdx.x * 64 + wave * 16 + l15;
    bool valid = row < N_NODES;

    // hoisted A-fragment loads: 8 independent 16B loads in flight
    bf16x8 zr[8];
#pragma unroll
    for (int kk = 0; kk < 8; ++kk)
        zr[kk] = valid ? *(const bf16x8*)(z1 + (size_t)row * D2 + kk * 32 + kg * 8)
                       : (bf16x8){0,0,0,0,0,0,0,0};

    f32x4 acc[8];
#pragma unroll
    for (int t = 0; t < 8; ++t) acc[t] = (f32x4){0,0,0,0};

#pragma unroll
    for (int kk = 0; kk < 8; ++kk) {
        int k0 = kk * 32 + kg * 8;
        const f32x4* sp = (const f32x4*)(scale + k0);
        const f32x4* tp = (const f32x4*)(shift + k0);
        f32x4 s0 = sp[0], s1 = sp[1], t0 = tp[0], t1 = tp[1];
        bf16x8 a;
#pragma unroll
        for (int j = 0; j < 4; ++j) {
            float v0 = fmaxf(bf2f((unsigned short)zr[kk][j]) * s0[j] + t0[j], 0.f);
            float v1 = fmaxf(bf2f((unsigned short)zr[kk][j + 4]) * s1[j] + t1[j], 0.f);
            a[j]     = (short)f2bf(v0);
            a[j + 4] = (short)f2bf(v1);
        }
        if (!valid) a = (bf16x8){0,0,0,0,0,0,0,0};
#pragma unroll
        for (int t = 0; t < 8; ++t) {
            bf16x8 b = *(const bf16x8*)(w2t + (t * 16 + l15) * D2 + kk * 32 + kg * 8);
            acc[t] = __builtin_amdgcn_mfma_f32_16x16x32_bf16(a, b, acc[t], 0, 0, 0);
        }
    }

    int orow = blockIdx.x * 64 + wave * 16 + kg * 4;
#pragma unroll
    for (int t = 0; t < 8; ++t) {
        int col = t * 16 + l15;
        float bias = b2[col];
        float sv = 0.f, qv = 0.f;
#pragma unroll
        for (int r = 0; r < 4; ++r) {
            int rr = orow + r;
            if (rr < N_NODES) {
                unsigned short us = f2bf(acc[t][r] + bias);
                z2[(size_t)rr * D + col] = us;
                float v = bf2f(us);
                sv += v;
                qv += v * v;
            }
        }
        sv += __shfl_xor(sv, 16); sv += __shfl_xor(sv, 32);
        qv += __shfl_xor(qv, 16); qv += __shfl_xor(qv, 32);
        if (kg == (t & 3)) {
            atomicAdd(&ssum[col], sv);
            atomicAdd(&ssq[col], qv);
        }
    }
    __syncthreads();
    if (threadIdx.x < D) {
        part2[(size_t)blockIdx.x * 256 + threadIdx.x] = ssum[threadIdx.x];
        part2[(size_t)blockIdx.x * 256 + 128 + threadIdx.x] = ssq[threadIdx.x];
    }
}

// ---------------- final: h = (relu?)(bn2(z2)) + h ----------------
__global__ __launch_bounds__(256) void final_kernel(const unsigned short* __restrict__ z2,
        const float* __restrict__ scale, const float* __restrict__ shift,
        float* __restrict__ h, int do_relu) {
    int i = blockIdx.x * 256 + threadIdx.x;
    int base = i * 4;
    int c = base & (D - 1);
    f32x4 sc = *(const f32x4*)(scale + c);
    f32x4 sh = *(const f32x4*)(shift + c);
    ushort4v zv = *(const ushort4v*)(z2 + base);
    f32x4 hv = *(const f32x4*)(h + base);
    f32x4 o;
#pragma unroll
    for (int j = 0; j < 4; ++j) {
        float v = bf2f(zv[j]) * sc[j] + sh[j];
        if (do_relu) v = fmaxf(v, 0.f);
        o[j] = v + hv[j];
    }
    *(f32x4*)(h + base) = o;
}

extern "C" void kernel_launch(void* const* d_in, const int* in_sizes, int n_in,
                              void* d_out, int out_size, void* d_ws, size_t ws_size,
                              hipStream_t stream) {
    const int* x = (const int*)d_in[0];
    const int* ei = (const int*)d_in[1];
    const int* ea = (const int*)d_in[2];
    const float* aemb = (const float*)d_in[4];
    const float* bemb = (const float*)d_in[5];
    const float* eps = (const float*)d_in[6];
    const float* W1 = (const float*)d_in[7];
    const float* b1 = (const float*)d_in[8];
    const float* bn1g = (const float*)d_in[9];
    const float* bn1b = (const float*)d_in[10];
    const float* W2 = (const float*)d_in[11];
    const float* b2 = (const float*)d_in[12];
    const float* bng = (const float*)d_in[13];
    const float* bnb = (const float*)d_in[14];
    float* h = (float*)d_out;

    char* ws = (char*)d_ws;
    size_t off = 0;
    auto alloc = [&](size_t bytes) {
        void* p = ws + off;
        off += (bytes + 255) & ~(size_t)255;
        return p;
    };
    unsigned short* z1  = (unsigned short*)alloc((size_t)N_NODES * D2 * 2);  // 76.8MB
    unsigned short* Az2 = (unsigned short*)alloc((size_t)N_NODES * D * 2);   // 38.4MB (A aliases z2)
    unsigned short* w1t = (unsigned short*)alloc((size_t)NLAYER * D2 * D * 2);
    unsigned short* w2t = (unsigned short*)alloc((size_t)NLAYER * D * D2 * 2);
    float* combo        = (float*)alloc((size_t)NLAYER * 216 * D * 4);
    int* bins           = (int*)alloc((size_t)N_EDGES * 4);
    int* row_start      = (int*)alloc((size_t)(NB1 * 256) * 4);
    int* deg            = (int*)alloc((size_t)(NB1 * 256) * 4);
    int* cursor         = (int*)alloc((size_t)(NB1 * 256) * 4);
    int* part           = (int*)alloc((size_t)(NB1 * 256) * 4);
    int* bsum           = (int*)alloc(1024 * 4);
    int* boff           = (int*)alloc(1024 * 4);
    float* part1        = (float*)alloc((size_t)NBG * 512 * 4);   // 4.8MB
    float* part2        = (float*)alloc((size_t)NBG * 256 * 4);   // 2.4MB
    float* scale1 = (float*)alloc(256 * 4);
    float* shift1 = (float*)alloc(256 * 4);
    float* scale2 = (float*)alloc(128 * 4);
    float* shift2 = (float*)alloc(128 * 4);

    // one-time prep
    prepw_kernel<<<(NLAYER * D2 * D + 255) / 256, 256, 0, stream>>>(W1, W2, w1t, w2t);
    combo_kernel<<<NLAYER * 216, 128, 0, stream>>>(bemb, combo);
    atom_enc_kernel<<<N_NODES / 8, 256, 0, stream>>>(x, aemb, h);

    // CSR build (by dst)
    hipMemsetAsync(deg, 0, (size_t)(NB1 * 256) * 4, stream);
    hipMemsetAsync(cursor, 0, (size_t)(NB1 * 256) * 4, stream);
    hist_kernel<<<(N_EDGES + 255) / 256, 256, 0, stream>>>(ei, deg);
    scan1_kernel<<<NB1, 256, 0, stream>>>(deg, part, bsum);
    scan2_kernel<<<1, 1024, 0, stream>>>(bsum, boff);
    scan3_kernel<<<NB1, 256, 0, stream>>>(part, boff, row_start);
    bin_kernel<<<(N_EDGES + 255) / 256, 256, 0, stream>>>(ei, ea, row_start, cursor, bins);

    for (int l = 0; l < NLAYER; ++l) {
        aggr_kernel<<<N_NODES / 8, 256, 0, stream>>>(row_start, deg, bins,
                combo + l * 216 * D, h, eps + l, Az2);
        gemm1_kernel<<<NBG, 256, 0, stream>>>(Az2, w1t + l * D2 * D,
                b1 + l * D2, z1, part1);
        reduce_finalize_kernel<<<256, 256, 0, stream>>>(part1, NBG, D2,
                bn1g + l * D2, bn1b + l * D2, scale1, shift1);
        gemm2_kernel<<<NBG, 256, 0, stream>>>(z1, scale1, shift1,
                w2t + l * D * D2, b2 + l * D, Az2, part2);
        reduce_finalize_kernel<<<128, 256, 0, stream>>>(part2, NBG, D,
                bng + l * D, bnb + l * D, scale2, shift2);
        final_kernel<<<(N_NODES * D / 4) / 256, 256, 0, stream>>>(Az2, scale2, shift2, h,
                (l < NLAYER - 1) ? 1 : 0);
    }
}

// Round 7
// 987.165 us; speedup vs baseline: 3.8343x; 1.8998x over previous
//
#include <hip/hip_runtime.h>

#define N_NODES 150000
#define N_EDGES 500000
#define D 128
#define D2 256
#define NLAYER 5
#define NB1 586    // ceil(N_NODES/256)
#define NROWT 9375 // N_NODES/16 (exact)
#define NBLK1 768  // gemm1 persistent blocks
#define NBLK2 512  // gemm2 persistent blocks

typedef __attribute__((ext_vector_type(8))) short bf16x8;
typedef __attribute__((ext_vector_type(4))) float f32x4;
typedef __attribute__((ext_vector_type(4))) unsigned short ushort4v;

__device__ __forceinline__ unsigned short f2bf(float f) {
    unsigned int u = __builtin_bit_cast(unsigned int, f);
    u += 0x7fffu + ((u >> 16) & 1u);
    return (unsigned short)(u >> 16);
}
__device__ __forceinline__ float bf2f(unsigned short s) {
    unsigned int u = ((unsigned int)s) << 16;
    return __builtin_bit_cast(float, u);
}

// ---------------- weight transpose + bf16 convert ----------------
__global__ __launch_bounds__(256) void prepw_kernel(const float* __restrict__ W1,
        const float* __restrict__ W2, unsigned short* __restrict__ w1t,
        unsigned short* __restrict__ w2t) {
    int i = blockIdx.x * 256 + threadIdx.x;
    if (i < NLAYER * D2 * D) {
        int l = i / (D2 * D);
        int rem = i % (D2 * D);
        int n = rem / D;
        int k = rem % D;
        w1t[i] = f2bf(W1[(l * D + k) * D2 + n]);
    }
    if (i < NLAYER * D * D2) {
        int l = i / (D * D2);
        int rem = i % (D * D2);
        int n = rem / D2;
        int k = rem % D2;
        w2t[i] = f2bf(W2[(l * D2 + k) * D + n]);
    }
}

// ---------------- bond combo table: combo[l][p][d], p = a0 + 6*a1 + 36*a2 ----------------
__global__ __launch_bounds__(128) void combo_kernel(const float* __restrict__ bemb,
        float* __restrict__ combo) {
    int b = blockIdx.x;            // l*216 + p
    int l = b / 216, p = b % 216;
    int a0 = p % 6, a1 = (p / 6) % 6, a2 = p / 36;
    int d = threadIdx.x;
    combo[b * D + d] = bemb[((l * 3 + 0) * 6 + a0) * D + d]
                     + bemb[((l * 3 + 1) * 6 + a1) * D + d]
                     + bemb[((l * 3 + 2) * 6 + a2) * D + d];
}

// ---------------- atom encoder ----------------
__global__ __launch_bounds__(256) void atom_enc_kernel(const int* __restrict__ x,
        const float* __restrict__ aemb, float* __restrict__ h) {
    int node = blockIdx.x * 8 + (threadIdx.x >> 5);
    int t = threadIdx.x & 31;
    int d0 = t * 4;
    f32x4 s = {0, 0, 0, 0};
#pragma unroll
    for (int f = 0; f < 9; ++f) {
        int xi = x[node * 9 + f];
        f32x4 v = *(const f32x4*)(aemb + (size_t)(f * 119 + xi) * D + d0);
        s[0] += v[0]; s[1] += v[1]; s[2] += v[2]; s[3] += v[3];
    }
    *(f32x4*)(h + (size_t)node * D + d0) = s;
}

// ---------------- CSR build ----------------
__global__ __launch_bounds__(256) void hist_kernel(const int* __restrict__ ei,
        int* __restrict__ deg) {
    int e = blockIdx.x * 256 + threadIdx.x;
    if (e < N_EDGES) atomicAdd(&deg[ei[N_EDGES + e]], 1);
}

__global__ __launch_bounds__(256) void scan1_kernel(const int* __restrict__ deg,
        int* __restrict__ part, int* __restrict__ bsum) {
    __shared__ int sd[256];
    int tid = threadIdx.x;
    int i = blockIdx.x * 256 + tid;
    int v = (i < N_NODES) ? deg[i] : 0;
    sd[tid] = v;
    __syncthreads();
    for (int off = 1; off < 256; off <<= 1) {
        int t = (tid >= off) ? sd[tid - off] : 0;
        __syncthreads();
        sd[tid] += t;
        __syncthreads();
    }
    if (i < N_NODES) part[i] = sd[tid] - v;
    if (tid == 255) bsum[blockIdx.x] = sd[255];
}

__global__ __launch_bounds__(1024) void scan2_kernel(const int* __restrict__ bsum,
        int* __restrict__ boff) {
    __shared__ int sd[1024];
    int tid = threadIdx.x;
    int v = (tid < NB1) ? bsum[tid] : 0;
    sd[tid] = v;
    __syncthreads();
    for (int off = 1; off < 1024; off <<= 1) {
        int t = (tid >= off) ? sd[tid - off] : 0;
        __syncthreads();
        sd[tid] += t;
        __syncthreads();
    }
    if (tid < NB1) boff[tid] = sd[tid] - v;
}

__global__ __launch_bounds__(256) void scan3_kernel(const int* __restrict__ part,
        const int* __restrict__ boff, int* __restrict__ row_start) {
    int i = blockIdx.x * 256 + threadIdx.x;
    if (i < N_NODES) row_start[i] = part[i] + boff[i >> 8];
}

__global__ __launch_bounds__(256) void bin_kernel(const int* __restrict__ ei,
        const int* __restrict__ ea, const int* __restrict__ row_start,
        int* __restrict__ cursor, int* __restrict__ bins) {
    int e = blockIdx.x * 256 + threadIdx.x;
    if (e >= N_EDGES) return;
    int dst = ei[N_EDGES + e];
    int pos = row_start[dst] + atomicAdd(&cursor[dst], 1);
    int pack = ea[e * 3 + 0] + ea[e * 3 + 1] * 6 + ea[e * 3 + 2] * 36;
    bins[pos] = ei[e] | (pack << 18);
}

// ---------------- aggregation + A-build: A = bf16((1+eps)h + sum relu(h[src]+e)) ----------------
__global__ __launch_bounds__(256) void aggr_kernel(const int* __restrict__ row_start,
        const int* __restrict__ deg, const int* __restrict__ bins,
        const float* __restrict__ combo, const float* __restrict__ h,
        const float* __restrict__ epsp, unsigned short* __restrict__ A) {
    int node = blockIdx.x * 8 + (threadIdx.x >> 5);
    int t = threadIdx.x & 31;
    int d0 = t * 4;
    float ke = 1.0f + epsp[0];
    int start = row_start[node];
    int dg = deg[node];
    f32x4 s = {0, 0, 0, 0};
    int entry = (dg > 0) ? bins[start] : 0;
    for (int i = 0; i < dg; ++i) {
        int next = (i + 1 < dg) ? bins[start + i + 1] : 0;
        int src = entry & 0x3FFFF;
        int pack = entry >> 18;
        f32x4 hv = *(const f32x4*)(h + (size_t)src * D + d0);
        f32x4 cv = *(const f32x4*)(combo + pack * D + d0);
#pragma unroll
        for (int j = 0; j < 4; ++j) s[j] += fmaxf(hv[j] + cv[j], 0.f);
        entry = next;
    }
    f32x4 hs = *(const f32x4*)(h + (size_t)node * D + d0);
    ushort4v o;
#pragma unroll
    for (int j = 0; j < 4; ++j) o[j] = f2bf(ke * hs[j] + s[j]);
    *(ushort4v*)(A + (size_t)node * D + d0) = o;
}

// ---------------- GEMM1 (persistent, B-resident): z1 = bf16(A @ W1 + b1) ----------------
// grid = NBLK1 blocks x 256 thr; wave owns cols [wave*64, wave*64+64); loops row-tiles.
__global__ __launch_bounds__(256) void gemm1_kernel(const unsigned short* __restrict__ A,
        const unsigned short* __restrict__ w1t, const float* __restrict__ b1,
        unsigned short* __restrict__ z1, float* __restrict__ part1) {
    int wave = threadIdx.x >> 6;
    int lane = threadIdx.x & 63;
    int l15 = lane & 15;
    int kg = lane >> 4;

    bf16x8 B[4][4];
    float bias[4];
#pragma unroll
    for (int t = 0; t < 4; ++t) {
        int col = (wave * 4 + t) * 16 + l15;
        bias[t] = b1[col];
#pragma unroll
        for (int kk = 0; kk < 4; ++kk)
            B[t][kk] = *(const bf16x8*)(w1t + (size_t)col * D + kk * 32 + kg * 8);
    }
    float s[4] = {0.f, 0.f, 0.f, 0.f}, q[4] = {0.f, 0.f, 0.f, 0.f};

    int rt = blockIdx.x;
    bf16x8 afn[4];
    {
        int row = rt * 16 + l15;
#pragma unroll
        for (int kk = 0; kk < 4; ++kk)
            afn[kk] = *(const bf16x8*)(A + (size_t)row * D + kk * 32 + kg * 8);
    }
    while (rt < NROWT) {
        int rtn = rt + NBLK1;
        bf16x8 af[4];
#pragma unroll
        for (int kk = 0; kk < 4; ++kk) af[kk] = afn[kk];
        if (rtn < NROWT) {
            int row = rtn * 16 + l15;
#pragma unroll
            for (int kk = 0; kk < 4; ++kk)
                afn[kk] = *(const bf16x8*)(A + (size_t)row * D + kk * 32 + kg * 8);
        }
        f32x4 acc[4];
#pragma unroll
        for (int t = 0; t < 4; ++t) acc[t] = (f32x4){0.f, 0.f, 0.f, 0.f};
#pragma unroll
        for (int kk = 0; kk < 4; ++kk)
#pragma unroll
            for (int t = 0; t < 4; ++t)
                acc[t] = __builtin_amdgcn_mfma_f32_16x16x32_bf16(af[kk], B[t][kk], acc[t], 0, 0, 0);
        int orow = rt * 16 + kg * 4;
#pragma unroll
        for (int t = 0; t < 4; ++t) {
            int col = (wave * 4 + t) * 16 + l15;
#pragma unroll
            for (int r = 0; r < 4; ++r) {
                unsigned short us = f2bf(acc[t][r] + bias[t]);
                z1[(size_t)(orow + r) * D2 + col] = us;
                float v = bf2f(us);
                s[t] += v; q[t] += v * v;
            }
        }
        rt = rtn;
    }
#pragma unroll
    for (int t = 0; t < 4; ++t) {
        s[t] += __shfl_xor(s[t], 16); s[t] += __shfl_xor(s[t], 32);
        q[t] += __shfl_xor(q[t], 16); q[t] += __shfl_xor(q[t], 32);
        if (kg == 0) {
            int col = (wave * 4 + t) * 16 + l15;
            part1[(size_t)blockIdx.x * 512 + col] = s[t];
            part1[(size_t)blockIdx.x * 512 + 256 + col] = q[t];
        }
    }
}

// ---------------- reduce partials + finalize BN (f32 + bf16 scale/shift) ----------------
__global__ __launch_bounds__(256) void reduce_finalize_kernel(const float* __restrict__ part,
        int nblk, int C, const float* __restrict__ g, const float* __restrict__ bb,
        float* __restrict__ scale, float* __restrict__ shift,
        unsigned short* __restrict__ scb, unsigned short* __restrict__ shb) {
    int c = blockIdx.x;
    int tid = threadIdx.x;
    float s = 0.f, q = 0.f;
    for (int i = tid; i < nblk; i += 256) {
        s += part[(size_t)i * 2 * C + c];
        q += part[(size_t)i * 2 * C + C + c];
    }
#pragma unroll
    for (int off = 1; off < 64; off <<= 1) {
        s += __shfl_xor(s, off);
        q += __shfl_xor(q, off);
    }
    __shared__ float rs[4], rq[4];
    int w = tid >> 6;
    if ((tid & 63) == 0) { rs[w] = s; rq[w] = q; }
    __syncthreads();
    if (tid == 0) {
        s = rs[0] + rs[1] + rs[2] + rs[3];
        q = rq[0] + rq[1] + rq[2] + rq[3];
        float inv_n = 1.0f / (float)N_NODES;
        float mean = s * inv_n;
        float var = q * inv_n - mean * mean;
        float sc = g[c] * rsqrtf(var + 1e-5f);
        float sh = bb[c] - mean * sc;
        scale[c] = sc;
        shift[c] = sh;
        scb[c] = f2bf(sc);
        shb[c] = f2bf(sh);
    }
}

// ---------------- GEMM2 (persistent, B+BN-resident): z2 = bf16(relu(bn1(z1)) @ W2 + b2) ----------------
// grid = NBLK2 blocks x 256 thr; wave owns cols [wave*32, wave*32+32).
__global__ __launch_bounds__(256) void gemm2_kernel(const unsigned short* __restrict__ z1,
        const unsigned short* __restrict__ scb, const unsigned short* __restrict__ shb,
        const unsigned short* __restrict__ w2t, const float* __restrict__ b2,
        unsigned short* __restrict__ z2, float* __restrict__ part2) {
    int wave = threadIdx.x >> 6;
    int lane = threadIdx.x & 63;
    int l15 = lane & 15;
    int kg = lane >> 4;

    bf16x8 B[2][8];
    float bias[2];
#pragma unroll
    for (int t = 0; t < 2; ++t) {
        int col = (wave * 2 + t) * 16 + l15;
        bias[t] = b2[col];
#pragma unroll
        for (int kk = 0; kk < 8; ++kk)
            B[t][kk] = *(const bf16x8*)(w2t + (size_t)col * D2 + kk * 32 + kg * 8);
    }
    bf16x8 sc[8], sh[8];
#pragma unroll
    for (int kk = 0; kk < 8; ++kk) {
        sc[kk] = *(const bf16x8*)(scb + kk * 32 + kg * 8);
        sh[kk] = *(const bf16x8*)(shb + kk * 32 + kg * 8);
    }
    float s[2] = {0.f, 0.f}, q[2] = {0.f, 0.f};

    int rt = blockIdx.x;
    bf16x8 zrn[8];
    {
        int row = rt * 16 + l15;
#pragma unroll
        for (int kk = 0; kk < 8; ++kk)
            zrn[kk] = *(const bf16x8*)(z1 + (size_t)row * D2 + kk * 32 + kg * 8);
    }
    while (rt < NROWT) {
        int rtn = rt + NBLK2;
        // convert current tile (frees zrn for prefetch)
        bf16x8 a[8];
#pragma unroll
        for (int kk = 0; kk < 8; ++kk) {
#pragma unroll
            for (int j = 0; j < 4; ++j) {
                float v0 = fmaxf(bf2f((unsigned short)zrn[kk][j]) * bf2f((unsigned short)sc[kk][j])
                                 + bf2f((unsigned short)sh[kk][j]), 0.f);
                float v1 = fmaxf(bf2f((unsigned short)zrn[kk][j + 4]) * bf2f((unsigned short)sc[kk][j + 4])
                                 + bf2f((unsigned short)sh[kk][j + 4]), 0.f);
                a[kk][j]     = (short)f2bf(v0);
                a[kk][j + 4] = (short)f2bf(v1);
            }
        }
        if (rtn < NROWT) {
            int row = rtn * 16 + l15;
#pragma unroll
            for (int kk = 0; kk < 8; ++kk)
                zrn[kk] = *(const bf16x8*)(z1 + (size_t)row * D2 + kk * 32 + kg * 8);
        }
        f32x4 acc[2];
        acc[0] = (f32x4){0.f, 0.f, 0.f, 0.f};
        acc[1] = (f32x4){0.f, 0.f, 0.f, 0.f};
#pragma unroll
        for (int kk = 0; kk < 8; ++kk) {
            acc[0] = __builtin_amdgcn_mfma_f32_16x16x32_bf16(a[kk], B[0][kk], acc[0], 0, 0, 0);
            acc[1] = __builtin_amdgcn_mfma_f32_16x16x32_bf16(a[kk], B[1][kk], acc[1], 0, 0, 0);
        }
        int orow = rt * 16 + kg * 4;
#pragma unroll
        for (int t = 0; t < 2; ++t) {
            int col = (wave * 2 + t) * 16 + l15;
#pragma unroll
            for (int r = 0; r < 4; ++r) {
                unsigned short us = f2bf(acc[t][r] + bias[t]);
                z2[(size_t)(orow + r) * D + col] = us;
                float v = bf2f(us);
                s[t] += v; q[t] += v * v;
            }
        }
        rt = rtn;
    }
#pragma unroll
    for (int t = 0; t < 2; ++t) {
        s[t] += __shfl_xor(s[t], 16); s[t] += __shfl_xor(s[t], 32);
        q[t] += __shfl_xor(q[t], 16); q[t] += __shfl_xor(q[t], 32);
        if (kg == 0) {
            int col = (wave * 2 + t) * 16 + l15;
            part2[(size_t)blockIdx.x * 256 + col] = s[t];
            part2[(size_t)blockIdx.x * 256 + 128 + col] = q[t];
        }
    }
}

// ---------------- final: h = (relu?)(bn2(z2)) + h ----------------
__global__ __launch_bounds__(256) void final_kernel(const unsigned short* __restrict__ z2,
        const float* __restrict__ scale, const float* __restrict__ shift,
        float* __restrict__ h, int do_relu) {
    int i = blockIdx.x * 256 + threadIdx.x;
    int base = i * 4;
    int c = base & (D - 1);
    f32x4 sc = *(const f32x4*)(scale + c);
    f32x4 sh = *(const f32x4*)(shift + c);
    ushort4v zv = *(const ushort4v*)(z2 + base);
    f32x4 hv = *(const f32x4*)(h + base);
    f32x4 o;
#pragma unroll
    for (int j = 0; j < 4; ++j) {
        float v = bf2f(zv[j]) * sc[j] + sh[j];
        if (do_relu) v = fmaxf(v, 0.f);
        o[j] = v + hv[j];
    }
    *(f32x4*)(h + base) = o;
}

extern "C" void kernel_launch(void* const* d_in, const int* in_sizes, int n_in,
                              void* d_out, int out_size, void* d_ws, size_t ws_size,
                              hipStream_t stream) {
    const int* x = (const int*)d_in[0];
    const int* ei = (const int*)d_in[1];
    const int* ea = (const int*)d_in[2];
    const float* aemb = (const float*)d_in[4];
    const float* bemb = (const float*)d_in[5];
    const float* eps = (const float*)d_in[6];
    const float* W1 = (const float*)d_in[7];
    const float* b1 = (const float*)d_in[8];
    const float* bn1g = (const float*)d_in[9];
    const float* bn1b = (const float*)d_in[10];
    const float* W2 = (const float*)d_in[11];
    const float* b2 = (const float*)d_in[12];
    const float* bng = (const float*)d_in[13];
    const float* bnb = (const float*)d_in[14];
    float* h = (float*)d_out;

    char* ws = (char*)d_ws;
    size_t off = 0;
    auto alloc = [&](size_t bytes) {
        void* p = ws + off;
        off += (bytes + 255) & ~(size_t)255;
        return p;
    };
    unsigned short* z1  = (unsigned short*)alloc((size_t)N_NODES * D2 * 2);  // 76.8MB
    unsigned short* Az2 = (unsigned short*)alloc((size_t)N_NODES * D * 2);   // 38.4MB (A aliases z2)
    unsigned short* w1t = (unsigned short*)alloc((size_t)NLAYER * D2 * D * 2);
    unsigned short* w2t = (unsigned short*)alloc((size_t)NLAYER * D * D2 * 2);
    float* combo        = (float*)alloc((size_t)NLAYER * 216 * D * 4);
    int* bins           = (int*)alloc((size_t)N_EDGES * 4);
    int* row_start      = (int*)alloc((size_t)(NB1 * 256) * 4);
    int* deg            = (int*)alloc((size_t)(NB1 * 256) * 4);
    int* cursor         = (int*)alloc((size_t)(NB1 * 256) * 4);
    int* part           = (int*)alloc((size_t)(NB1 * 256) * 4);
    int* bsum           = (int*)alloc(1024 * 4);
    int* boff           = (int*)alloc(1024 * 4);
    float* part1        = (float*)alloc((size_t)NBLK1 * 512 * 4);   // 1.6MB
    float* part2        = (float*)alloc((size_t)NBLK2 * 256 * 4);   // 0.5MB
    float* scale1 = (float*)alloc(256 * 4);
    float* shift1 = (float*)alloc(256 * 4);
    float* scale2 = (float*)alloc(128 * 4);
    float* shift2 = (float*)alloc(128 * 4);
    unsigned short* scb1 = (unsigned short*)alloc(256 * 2);
    unsigned short* shb1 = (unsigned short*)alloc(256 * 2);
    unsigned short* scb2 = (unsigned short*)alloc(128 * 2);
    unsigned short* shb2 = (unsigned short*)alloc(128 * 2);

    // one-time prep
    prepw_kernel<<<(NLAYER * D2 * D + 255) / 256, 256, 0, stream>>>(W1, W2, w1t, w2t);
    combo_kernel<<<NLAYER * 216, 128, 0, stream>>>(bemb, combo);
    atom_enc_kernel<<<N_NODES / 8, 256, 0, stream>>>(x, aemb, h);

    // CSR build (by dst)
    hipMemsetAsync(deg, 0, (size_t)(NB1 * 256) * 4, stream);
    hipMemsetAsync(cursor, 0, (size_t)(NB1 * 256) * 4, stream);
    hist_kernel<<<(N_EDGES + 255) / 256, 256, 0, stream>>>(ei, deg);
    scan1_kernel<<<NB1, 256, 0, stream>>>(deg, part, bsum);
    scan2_kernel<<<1, 1024, 0, stream>>>(bsum, boff);
    scan3_kernel<<<NB1, 256, 0, stream>>>(part, boff, row_start);
    bin_kernel<<<(N_EDGES + 255) / 256, 256, 0, stream>>>(ei, ea, row_start, cursor, bins);

    for (int l = 0; l < NLAYER; ++l) {
        aggr_kernel<<<N_NODES / 8, 256, 0, stream>>>(row_start, deg, bins,
                combo + l * 216 * D, h, eps + l, Az2);
        gemm1_kernel<<<NBLK1, 256, 0, stream>>>(Az2, w1t + l * D2 * D,
                b1 + l * D2, z1, part1);
        reduce_finalize_kernel<<<256, 256, 0, stream>>>(part1, NBLK1, D2,
                bn1g + l * D2, bn1b + l * D2, scale1, shift1, scb1, shb1);
        gemm2_kernel<<<NBLK2, 256, 0, stream>>>(z1, scb1, shb1,
                w2t + l * D * D2, b2 + l * D, Az2, part2);
        reduce_finalize_kernel<<<128, 256, 0, stream>>>(part2, NBLK2, D,
                bng + l * D, bnb + l * D, scale2, shift2, scb2, shb2);
        final_kernel<<<(N_NODES * D / 4) / 256, 256, 0, stream>>>(Az2, scale2, shift2, h,
                (l < NLAYER - 1) ? 1 : 0);
    }
}

// Round 9
// 954.949 us; speedup vs baseline: 3.9636x; 1.0337x over previous
//
#include <hip/hip_runtime.h>

#define N_NODES 150000
#define N_EDGES 500000
#define D 128
#define D2 256
#define NLAYER 5
#define NB1 586    // ceil(N_NODES/256)
#define NROWT 9375 // N_NODES/16 (exact)
#define NBLK1 768  // gemm1 persistent blocks
#define NBLK2 512  // gemm2 persistent blocks

typedef __attribute__((ext_vector_type(8))) short bf16x8;
typedef __attribute__((ext_vector_type(4))) float f32x4;
typedef __attribute__((ext_vector_type(4))) unsigned short ushort4v;
typedef __attribute__((ext_vector_type(8))) unsigned short ushort8v;

__device__ __forceinline__ unsigned short f2bf(float f) {
    unsigned int u = __builtin_bit_cast(unsigned int, f);
    u += 0x7fffu + ((u >> 16) & 1u);
    return (unsigned short)(u >> 16);
}
__device__ __forceinline__ float bf2f(unsigned short s) {
    unsigned int u = ((unsigned int)s) << 16;
    return __builtin_bit_cast(float, u);
}

// ---------------- weight transpose + bf16 convert ----------------
__global__ __launch_bounds__(256) void prepw_kernel(const float* __restrict__ W1,
        const float* __restrict__ W2, unsigned short* __restrict__ w1t,
        unsigned short* __restrict__ w2t) {
    int i = blockIdx.x * 256 + threadIdx.x;
    if (i < NLAYER * D2 * D) {
        int l = i / (D2 * D);
        int rem = i % (D2 * D);
        int n = rem / D;
        int k = rem % D;
        w1t[i] = f2bf(W1[(l * D + k) * D2 + n]);
    }
    if (i < NLAYER * D * D2) {
        int l = i / (D * D2);
        int rem = i % (D * D2);
        int n = rem / D2;
        int k = rem % D2;
        w2t[i] = f2bf(W2[(l * D2 + k) * D + n]);
    }
}

// ---------------- bond combo table ----------------
__global__ __launch_bounds__(128) void combo_kernel(const float* __restrict__ bemb,
        float* __restrict__ combo) {
    int b = blockIdx.x;            // l*216 + p
    int l = b / 216, p = b % 216;
    int a0 = p % 6, a1 = (p / 6) % 6, a2 = p / 36;
    int d = threadIdx.x;
    combo[b * D + d] = bemb[((l * 3 + 0) * 6 + a0) * D + d]
                     + bemb[((l * 3 + 1) * 6 + a1) * D + d]
                     + bemb[((l * 3 + 2) * 6 + a2) * D + d];
}

// ---------------- atom encoder (writes f32 h + bf16 shadow) ----------------
__global__ __launch_bounds__(256) void atom_enc_kernel(const int* __restrict__ x,
        const float* __restrict__ aemb, float* __restrict__ h,
        unsigned short* __restrict__ hbf) {
    int node = blockIdx.x * 8 + (threadIdx.x >> 5);
    int t = threadIdx.x & 31;
    int d0 = t * 4;
    f32x4 s = {0, 0, 0, 0};
#pragma unroll
    for (int f = 0; f < 9; ++f) {
        int xi = x[node * 9 + f];
        f32x4 v = *(const f32x4*)(aemb + (size_t)(f * 119 + xi) * D + d0);
        s[0] += v[0]; s[1] += v[1]; s[2] += v[2]; s[3] += v[3];
    }
    *(f32x4*)(h + (size_t)node * D + d0) = s;
    ushort4v o;
#pragma unroll
    for (int j = 0; j < 4; ++j) o[j] = f2bf(s[j]);
    *(ushort4v*)(hbf + (size_t)node * D + d0) = o;
}

// ---------------- CSR build ----------------
__global__ __launch_bounds__(256) void hist_kernel(const int* __restrict__ ei,
        int* __restrict__ deg) {
    int e = blockIdx.x * 256 + threadIdx.x;
    if (e < N_EDGES) atomicAdd(&deg[ei[N_EDGES + e]], 1);
}

__global__ __launch_bounds__(256) void scan1_kernel(const int* __restrict__ deg,
        int* __restrict__ part, int* __restrict__ bsum) {
    __shared__ int sd[256];
    int tid = threadIdx.x;
    int i = blockIdx.x * 256 + tid;
    int v = (i < N_NODES) ? deg[i] : 0;
    sd[tid] = v;
    __syncthreads();
    for (int off = 1; off < 256; off <<= 1) {
        int t = (tid >= off) ? sd[tid - off] : 0;
        __syncthreads();
        sd[tid] += t;
        __syncthreads();
    }
    if (i < N_NODES) part[i] = sd[tid] - v;
    if (tid == 255) bsum[blockIdx.x] = sd[255];
}

__global__ __launch_bounds__(1024) void scan2_kernel(const int* __restrict__ bsum,
        int* __restrict__ boff) {
    __shared__ int sd[1024];
    int tid = threadIdx.x;
    int v = (tid < NB1) ? bsum[tid] : 0;
    sd[tid] = v;
    __syncthreads();
    for (int off = 1; off < 1024; off <<= 1) {
        int t = (tid >= off) ? sd[tid - off] : 0;
        __syncthreads();
        sd[tid] += t;
        __syncthreads();
    }
    if (tid < NB1) boff[tid] = sd[tid] - v;
}

__global__ __launch_bounds__(256) void scan3_kernel(const int* __restrict__ part,
        const int* __restrict__ boff, int* __restrict__ row_start) {
    int i = blockIdx.x * 256 + threadIdx.x;
    if (i < N_NODES) row_start[i] = part[i] + boff[i >> 8];
}

__global__ __launch_bounds__(256) void bin_kernel(const int* __restrict__ ei,
        const int* __restrict__ ea, const int* __restrict__ row_start,
        int* __restrict__ cursor, int* __restrict__ bins) {
    int e = blockIdx.x * 256 + threadIdx.x;
    if (e >= N_EDGES) return;
    int dst = ei[N_EDGES + e];
    int pos = row_start[dst] + atomicAdd(&cursor[dst], 1);
    int pack = ea[e * 3 + 0] + ea[e * 3 + 1] * 6 + ea[e * 3 + 2] * 36;
    bins[pos] = ei[e] | (pack << 18);
}

// ---------------- aggregation + A-build (bf16 gather) ----------------
__global__ __launch_bounds__(256) void aggr_kernel(const int* __restrict__ row_start,
        const int* __restrict__ deg, const int* __restrict__ bins,
        const float* __restrict__ combo, const unsigned short* __restrict__ hbf,
        const float* __restrict__ epsp, unsigned short* __restrict__ A) {
    int node = blockIdx.x * 8 + (threadIdx.x >> 5);
    int t = threadIdx.x & 31;
    int d0 = t * 4;
    float ke = 1.0f + epsp[0];
    int start = row_start[node];
    int dg = deg[node];
    f32x4 s = {0, 0, 0, 0};
    int entry = (dg > 0) ? bins[start] : 0;
    for (int i = 0; i < dg; ++i) {
        int next = (i + 1 < dg) ? bins[start + i + 1] : 0;
        int src = entry & 0x3FFFF;
        int pack = entry >> 18;
        ushort4v hv4 = *(const ushort4v*)(hbf + (size_t)src * D + d0);
        f32x4 cv = *(const f32x4*)(combo + pack * D + d0);
#pragma unroll
        for (int j = 0; j < 4; ++j) s[j] += fmaxf(bf2f(hv4[j]) + cv[j], 0.f);
        entry = next;
    }
    ushort4v hs4 = *(const ushort4v*)(hbf + (size_t)node * D + d0);
    ushort4v o;
#pragma unroll
    for (int j = 0; j < 4; ++j) o[j] = f2bf(ke * bf2f(hs4[j]) + s[j]);
    *(ushort4v*)(A + (size_t)node * D + d0) = o;
}

// ---------------- GEMM1 (persistent, B-resident, LDS-staged stores) ----------------
__global__ __launch_bounds__(256) void gemm1_kernel(const unsigned short* __restrict__ A,
        const unsigned short* __restrict__ w1t, const float* __restrict__ b1,
        unsigned short* __restrict__ z1, float* __restrict__ part1) {
    __shared__ unsigned short sm[4][16][76];
    int wave = threadIdx.x >> 6;
    int lane = threadIdx.x & 63;
    int l15 = lane & 15;
    int kg = lane >> 4;
    int rrow = lane >> 3;          // 0..7
    int rcol = (lane & 7) * 8;     // 0..63 step 8

    bf16x8 B[4][4];
    float bias[4];
#pragma unroll
    for (int t = 0; t < 4; ++t) {
        int col = (wave * 4 + t) * 16 + l15;
        bias[t] = b1[col];
#pragma unroll
        for (int kk = 0; kk < 4; ++kk)
            B[t][kk] = *(const bf16x8*)(w1t + (size_t)col * D + kk * 32 + kg * 8);
    }
    float s[4] = {0.f, 0.f, 0.f, 0.f}, q[4] = {0.f, 0.f, 0.f, 0.f};

    int rt = blockIdx.x;
    bf16x8 afn[4];
    {
        int row = rt * 16 + l15;
#pragma unroll
        for (int kk = 0; kk < 4; ++kk)
            afn[kk] = *(const bf16x8*)(A + (size_t)row * D + kk * 32 + kg * 8);
    }
    while (rt < NROWT) {
        int rtn = rt + NBLK1;
        bf16x8 af[4];
#pragma unroll
        for (int kk = 0; kk < 4; ++kk) af[kk] = afn[kk];
        if (rtn < NROWT) {
            int row = rtn * 16 + l15;
#pragma unroll
            for (int kk = 0; kk < 4; ++kk)
                afn[kk] = *(const bf16x8*)(A + (size_t)row * D + kk * 32 + kg * 8);
        }
        f32x4 acc[4];
#pragma unroll
        for (int t = 0; t < 4; ++t) acc[t] = (f32x4){0.f, 0.f, 0.f, 0.f};
#pragma unroll
        for (int kk = 0; kk < 4; ++kk)
#pragma unroll
            for (int t = 0; t < 4; ++t)
                acc[t] = __builtin_amdgcn_mfma_f32_16x16x32_bf16(af[kk], B[t][kk], acc[t], 0, 0, 0);
#pragma unroll
        for (int t = 0; t < 4; ++t) {
#pragma unroll
            for (int r = 0; r < 4; ++r) {
                unsigned short us = f2bf(acc[t][r] + bias[t]);
                sm[wave][kg * 4 + r][t * 16 + l15] = us;
                float v = bf2f(us);
                s[t] += v; q[t] += v * v;
            }
        }
        // wave-private LDS round-trip (compiler inserts lgkmcnt waits)
        ushort8v v0 = *(const ushort8v*)&sm[wave][rrow][rcol];
        ushort8v v1 = *(const ushort8v*)&sm[wave][8 + rrow][rcol];
        *(ushort8v*)(z1 + (size_t)(rt * 16 + rrow) * D2 + wave * 64 + rcol) = v0;
        *(ushort8v*)(z1 + (size_t)(rt * 16 + 8 + rrow) * D2 + wave * 64 + rcol) = v1;
        rt = rtn;
    }
#pragma unroll
    for (int t = 0; t < 4; ++t) {
        s[t] += __shfl_xor(s[t], 16); s[t] += __shfl_xor(s[t], 32);
        q[t] += __shfl_xor(q[t], 16); q[t] += __shfl_xor(q[t], 32);
        if (kg == 0) {
            int col = (wave * 4 + t) * 16 + l15;
            part1[(size_t)blockIdx.x * 512 + col] = s[t];
            part1[(size_t)blockIdx.x * 512 + 256 + col] = q[t];
        }
    }
}

// ---------------- reduce partials + finalize BN ----------------
__global__ __launch_bounds__(256) void reduce_finalize_kernel(const float* __restrict__ part,
        int nblk, int C, const float* __restrict__ g, const float* __restrict__ bb,
        float* __restrict__ scale, float* __restrict__ shift,
        unsigned short* __restrict__ scb, unsigned short* __restrict__ shb) {
    int c = blockIdx.x;
    int tid = threadIdx.x;
    float s = 0.f, q = 0.f;
    for (int i = tid; i < nblk; i += 256) {
        s += part[(size_t)i * 2 * C + c];
        q += part[(size_t)i * 2 * C + C + c];
    }
#pragma unroll
    for (int off = 1; off < 64; off <<= 1) {
        s += __shfl_xor(s, off);
        q += __shfl_xor(q, off);
    }
    __shared__ float rs[4], rq[4];
    int w = tid >> 6;
    if ((tid & 63) == 0) { rs[w] = s; rq[w] = q; }
    __syncthreads();
    if (tid == 0) {
        s = rs[0] + rs[1] + rs[2] + rs[3];
        q = rq[0] + rq[1] + rq[2] + rq[3];
        float inv_n = 1.0f / (float)N_NODES;
        float mean = s * inv_n;
        float var = q * inv_n - mean * mean;
        float sc = g[c] * rsqrtf(var + 1e-5f);
        float sh = bb[c] - mean * sc;
        scale[c] = sc;
        shift[c] = sh;
        scb[c] = f2bf(sc);
        shb[c] = f2bf(sh);
    }
}

// ---------------- GEMM2 (persistent, B+BN-resident, LDS-staged stores) ----------------
__global__ __launch_bounds__(256) void gemm2_kernel(const unsigned short* __restrict__ z1,
        const unsigned short* __restrict__ scb, const unsigned short* __restrict__ shb,
        const unsigned short* __restrict__ w2t, const float* __restrict__ b2,
        unsigned short* __restrict__ z2, float* __restrict__ part2) {
    __shared__ unsigned short sm2[4][16][44];
    int wave = threadIdx.x >> 6;
    int lane = threadIdx.x & 63;
    int l15 = lane & 15;
    int kg = lane >> 4;
    int rrow = lane >> 2;          // 0..15
    int rcol = (lane & 3) * 8;     // 0..31 step 8

    bf16x8 B[2][8];
    float bias[2];
#pragma unroll
    for (int t = 0; t < 2; ++t) {
        int col = (wave * 2 + t) * 16 + l15;
        bias[t] = b2[col];
#pragma unroll
        for (int kk = 0; kk < 8; ++kk)
            B[t][kk] = *(const bf16x8*)(w2t + (size_t)col * D2 + kk * 32 + kg * 8);
    }
    bf16x8 sc[8], sh[8];
#pragma unroll
    for (int kk = 0; kk < 8; ++kk) {
        sc[kk] = *(const bf16x8*)(scb + kk * 32 + kg * 8);
        sh[kk] = *(const bf16x8*)(shb + kk * 32 + kg * 8);
    }
    float s[2] = {0.f, 0.f}, q[2] = {0.f, 0.f};

    int rt = blockIdx.x;
    bf16x8 zrn[8];
    {
        int row = rt * 16 + l15;
#pragma unroll
        for (int kk = 0; kk < 8; ++kk)
            zrn[kk] = *(const bf16x8*)(z1 + (size_t)row * D2 + kk * 32 + kg * 8);
    }
    while (rt < NROWT) {
        int rtn = rt + NBLK2;
        bf16x8 a[8];
#pragma unroll
        for (int kk = 0; kk < 8; ++kk) {
#pragma unroll
            for (int j = 0; j < 4; ++j) {
                float v0 = fmaxf(bf2f((unsigned short)zrn[kk][j]) * bf2f((unsigned short)sc[kk][j])
                                 + bf2f((unsigned short)sh[kk][j]), 0.f);
                float v1 = fmaxf(bf2f((unsigned short)zrn[kk][j + 4]) * bf2f((unsigned short)sc[kk][j + 4])
                                 + bf2f((unsigned short)sh[kk][j + 4]), 0.f);
                a[kk][j]     = (short)f2bf(v0);
                a[kk][j + 4] = (short)f2bf(v1);
            }
        }
        if (rtn < NROWT) {
            int row = rtn * 16 + l15;
#pragma unroll
            for (int kk = 0; kk < 8; ++kk)
                zrn[kk] = *(const bf16x8*)(z1 + (size_t)row * D2 + kk * 32 + kg * 8);
        }
        f32x4 acc[2];
        acc[0] = (f32x4){0.f, 0.f, 0.f, 0.f};
        acc[1] = (f32x4){0.f, 0.f, 0.f, 0.f};
#pragma unroll
        for (int kk = 0; kk < 8; ++kk) {
            acc[0] = __builtin_amdgcn_mfma_f32_16x16x32_bf16(a[kk], B[0][kk], acc[0], 0, 0, 0);
            acc[1] = __builtin_amdgcn_mfma_f32_16x16x32_bf16(a[kk], B[1][kk], acc[1], 0, 0, 0);
        }
#pragma unroll
        for (int t = 0; t < 2; ++t) {
#pragma unroll
            for (int r = 0; r < 4; ++r) {
                unsigned short us = f2bf(acc[t][r] + bias[t]);
                sm2[wave][kg * 4 + r][t * 16 + l15] = us;
                float v = bf2f(us);
                s[t] += v; q[t] += v * v;
            }
        }
        ushort8v v0 = *(const ushort8v*)&sm2[wave][rrow][rcol];
        *(ushort8v*)(z2 + (size_t)(rt * 16 + rrow) * D + wave * 32 + rcol) = v0;
        rt = rtn;
    }
#pragma unroll
    for (int t = 0; t < 2; ++t) {
        s[t] += __shfl_xor(s[t], 16); s[t] += __shfl_xor(s[t], 32);
        q[t] += __shfl_xor(q[t], 16); q[t] += __shfl_xor(q[t], 32);
        if (kg == 0) {
            int col = (wave * 2 + t) * 16 + l15;
            part2[(size_t)blockIdx.x * 256 + col] = s[t];
            part2[(size_t)blockIdx.x * 256 + 128 + col] = q[t];
        }
    }
}

// ---------------- final: h = (relu?)(bn2(z2)) + h  (+ bf16 shadow) ----------------
__global__ __launch_bounds__(256) void final_kernel(const unsigned short* __restrict__ z2,
        const float* __restrict__ scale, const float* __restrict__ shift,
        float* __restrict__ h, unsigned short* __restrict__ hbf,
        int do_relu, int write_bf) {
    int i = blockIdx.x * 256 + threadIdx.x;
    int base = i * 4;
    int c = base & (D - 1);
    f32x4 sc = *(const f32x4*)(scale + c);
    f32x4 sh = *(const f32x4*)(shift + c);
    ushort4v zv = *(const ushort4v*)(z2 + base);
    f32x4 hv = *(const f32x4*)(h + base);
    f32x4 o;
#pragma unroll
    for (int j = 0; j < 4; ++j) {
        float v = bf2f(zv[j]) * sc[j] + sh[j];
        if (do_relu) v = fmaxf(v, 0.f);
        o[j] = v + hv[j];
    }
    *(f32x4*)(h + base) = o;
    if (write_bf) {
        ushort4v ob;
#pragma unroll
        for (int j = 0; j < 4; ++j) ob[j] = f2bf(o[j]);
        *(ushort4v*)(hbf + base) = ob;
    }
}

extern "C" void kernel_launch(void* const* d_in, const int* in_sizes, int n_in,
                              void* d_out, int out_size, void* d_ws, size_t ws_size,
                              hipStream_t stream) {
    const int* x = (const int*)d_in[0];
    const int* ei = (const int*)d_in[1];
    const int* ea = (const int*)d_in[2];
    const float* aemb = (const float*)d_in[4];
    const float* bemb = (const float*)d_in[5];
    const float* eps = (const float*)d_in[6];
    const float* W1 = (const float*)d_in[7];
    const float* b1 = (const float*)d_in[8];
    const float* bn1g = (const float*)d_in[9];
    const float* bn1b = (const float*)d_in[10];
    const float* W2 = (const float*)d_in[11];
    const float* b2 = (const float*)d_in[12];
    const float* bng = (const float*)d_in[13];
    const float* bnb = (const float*)d_in[14];
    float* h = (float*)d_out;

    char* ws = (char*)d_ws;
    size_t off = 0;
    auto alloc = [&](size_t bytes) {
        void* p = ws + off;
        off += (bytes + 255) & ~(size_t)255;
        return p;
    };
    unsigned short* z1  = (unsigned short*)alloc((size_t)N_NODES * D2 * 2);  // 76.8MB
    unsigned short* Az2 = (unsigned short*)alloc((size_t)N_NODES * D * 2);   // 38.4MB (A aliases z2)
    unsigned short* hbf = (unsigned short*)alloc((size_t)N_NODES * D * 2);   // 38.4MB bf16 shadow of h
    unsigned short* w1t = (unsigned short*)alloc((size_t)NLAYER * D2 * D * 2);
    unsigned short* w2t = (unsigned short*)alloc((size_t)NLAYER * D * D2 * 2);
    float* combo        = (float*)alloc((size_t)NLAYER * 216 * D * 4);
    int* bins           = (int*)alloc((size_t)N_EDGES * 4);
    int* row_start      = (int*)alloc((size_t)(NB1 * 256) * 4);
    int* deg            = (int*)alloc((size_t)(NB1 * 256) * 4);
    int* cursor         = (int*)alloc((size_t)(NB1 * 256) * 4);
    int* part           = (int*)alloc((size_t)(NB1 * 256) * 4);
    int* bsum           = (int*)alloc(1024 * 4);
    int* boff           = (int*)alloc(1024 * 4);
    float* part1        = (float*)alloc((size_t)NBLK1 * 512 * 4);   // 1.6MB
    float* part2        = (float*)alloc((size_t)NBLK2 * 256 * 4);   // 0.5MB
    float* scale1 = (float*)alloc(256 * 4);
    float* shift1 = (float*)alloc(256 * 4);
    float* scale2 = (float*)alloc(128 * 4);
    float* shift2 = (float*)alloc(128 * 4);
    unsigned short* scb1 = (unsigned short*)alloc(256 * 2);
    unsigned short* shb1 = (unsigned short*)alloc(256 * 2);
    unsigned short* scb2 = (unsigned short*)alloc(128 * 2);
    unsigned short* shb2 = (unsigned short*)alloc(128 * 2);

    // one-time prep
    prepw_kernel<<<(NLAYER * D2 * D + 255) / 256, 256, 0, stream>>>(W1, W2, w1t, w2t);
    combo_kernel<<<NLAYER * 216, 128, 0, stream>>>(bemb, combo);
    atom_enc_kernel<<<N_NODES / 8, 256, 0, stream>>>(x, aemb, h, hbf);

    // CSR build (by dst)
    hipMemsetAsync(deg, 0, (size_t)(NB1 * 256) * 4, stream);
    hipMemsetAsync(cursor, 0, (size_t)(NB1 * 256) * 4, stream);
    hist_kernel<<<(N_EDGES + 255) / 256, 256, 0, stream>>>(ei, deg);
    scan1_kernel<<<NB1, 256, 0, stream>>>(deg, part, bsum);
    scan2_kernel<<<1, 1024, 0, stream>>>(bsum, boff);
    scan3_kernel<<<NB1, 256, 0, stream>>>(part, boff, row_start);
    bin_kernel<<<(N_EDGES + 255) / 256, 256, 0, stream>>>(ei, ea, row_start, cursor, bins);

    for (int l = 0; l < NLAYER; ++l) {
        aggr_kernel<<<N_NODES / 8, 256, 0, stream>>>(row_start, deg, bins,
                combo + l * 216 * D, hbf, eps + l, Az2);
        gemm1_kernel<<<NBLK1, 256, 0, stream>>>(Az2, w1t + l * D2 * D,
                b1 + l * D2, z1, part1);
        reduce_finalize_kernel<<<256, 256, 0, stream>>>(part1, NBLK1, D2,
                bn1g + l * D2, bn1b + l * D2, scale1, shift1, scb1, shb1);
        gemm2_kernel<<<NBLK2, 256, 0, stream>>>(z1, scb1, shb1,
                w2t + l * D * D2, b2 + l * D, Az2, part2);
        reduce_finalize_kernel<<<128, 256, 0, stream>>>(part2, NBLK2, D,
                bng + l * D, bnb + l * D, scale2, shift2, scb2, shb2);
        final_kernel<<<(N_NODES * D / 4) / 256, 256, 0, stream>>>(Az2, scale2, shift2, h, hbf,
                (l < NLAYER - 1) ? 1 : 0, (l < NLAYER - 1) ? 1 : 0);
    }
}